// Round 26
// baseline (540.839 us; speedup 1.0000x reference)
//
#include <hip/hip_runtime.h>
#include <hip/hip_bf16.h>

#define DEV __device__ __forceinline__

typedef __attribute__((ext_vector_type(8))) short s8v;   // 8 bf16 (4 VGPR)
typedef __attribute__((ext_vector_type(4))) float f4v;   // MFMA acc

static constexpr int NWIN = 1152;
static constexpr int NROW = 73728;

// ---------------- workspace layout (peak < 185.8 MB) ----
static constexpr size_t OFF_X1   = 132710400;    // f32  [NROW][180]  (live until pe/p2)
static constexpr size_t OFF_V1   = 0;            // f32  NCHW [8*96][9216]
static constexpr size_t OFF_AB1  = 28311552;     // f32  NCHW
static constexpr size_t OFF_AB2  = 84934656;     // f32  NCHW (dwcf output, no in-place race)
static constexpr size_t OFF_VNB  = 56623104;     // bf16 NHWC [NROW][192] — group-padded layout
static constexpr size_t OFF_CBN  = 0;            // bf16 NHWC [NROW][192] (over v1, dead)
static constexpr size_t WB       = 130613248;
static constexpr size_t O_TBL    = WB;                    // f32 [225][6]
static constexpr size_t O_BIASA  = WB + 8192;             // f32 [6][64][64]
static constexpr size_t O_WQ     = WB + 106496;           // bf16 packed frag-major [34*6*512]
static constexpr size_t O_WPJ    = O_WQ  + 208896;        // bf16 packed frag-major [12*6*512]
static constexpr size_t O_WPE    = O_WPJ + 73728;         // bf16 packed frag-major [12*6*512]
static constexpr size_t O_WP1    = O_WPE + 73728;         // bf16 [96][192]
static constexpr size_t O_WPW    = O_WP1 + 36864;         // bf16 [96][96]
static constexpr size_t O_WP2    = O_WPW + 18432;         // bf16 [192][96]
static constexpr size_t O_WF1    = O_WP2 + 36864;         // bf16 packed frag-major [45*6*512]
static constexpr size_t O_WF2    = O_WF1 + 282624;        // bf16 packed frag-major [12*23*512]
static constexpr size_t O_WCB    = O_WF2 + 282624;        // bf16 packed frag-major [2*9*6*3*512]

DEV float geluf(float x){ return 0.5f*x*(1.f + erff(x*0.70710678118654752f)); }

DEV unsigned short f2b(float v){
  union { __hip_bfloat16 h; unsigned short u; } x;
  x.h = __float2bfloat16(v);
  return x.u;
}

DEV float b2f(unsigned short u){
  union { float f; unsigned u; } x;
  x.u = ((unsigned)u) << 16;
  return x.f;
}

DEV f4v mfma16(s8v a, s8v b, f4v c){
  return __builtin_amdgcn_mfma_f32_16x16x32_bf16(a, b, c, 0, 0, 0);
}

DEV float rsum16(float v){
  v += __shfl_xor(v, 1); v += __shfl_xor(v, 2);
  v += __shfl_xor(v, 4); v += __shfl_xor(v, 8);
  return v;
}

DEV float rmax16(float v){
  v = fmaxf(v, __shfl_xor(v, 1)); v = fmaxf(v, __shfl_xor(v, 2));
  v = fmaxf(v, __shfl_xor(v, 4)); v = fmaxf(v, __shfl_xor(v, 8));
  return v;
}

DEV float qkvbias(int c, const float* qb, const float* vb){
  return (c < 180) ? qb[c] : (c < 360 ? 0.f : vb[c-360]);
}

DEV void pack4(unsigned short* dst, float4 v){
  unsigned p0 = (unsigned)f2b(v.x) | ((unsigned)f2b(v.y) << 16);
  unsigned p1 = (unsigned)f2b(v.z) | ((unsigned)f2b(v.w) << 16);
  uint2 pk; pk.x = p0; pk.y = p1;
  *(uint2*)dst = pk;
}

// ---------------- CPB MLP table ----------------
__global__ __launch_bounds__(512) void k_cpb_tbl(const float* __restrict__ w1,
    const float* __restrict__ b1, const float* __restrict__ w2, float* __restrict__ tbl){
  int m = blockIdx.x, tid = threadIdx.x;
  int i = m/15, j = m - (m/15)*15;
  float t0 = (float)(i-7)*(8.f/7.f), t1 = (float)(j-7)*(8.f/7.f);
  float f0 = log2f(fabsf(t0)+1.f)*(1.f/3.f); if (t0 < 0.f) f0 = -f0;
  float f1 = log2f(fabsf(t1)+1.f)*(1.f/3.f); if (t1 < 0.f) f1 = -f1;
  float hv = fmaxf(f0*w1[2*tid] + f1*w1[2*tid+1] + b1[tid], 0.f);
  __shared__ float red[6][8];
  int lane = tid & 63, wv = tid >> 6;
  for (int h = 0; h < 6; ++h) {
    float p = hv * w2[h*512 + tid];
    for (int off = 32; off; off >>= 1) p += __shfl_down(p, off);
    if (lane == 0) red[h][wv] = p;
  }
  __syncthreads();
  if (tid < 6) {
    float s = 0.f;
    for (int w = 0; w < 8; ++w) s += red[tid][w];
    tbl[m*6 + tid] = s;
  }
}

__global__ __launch_bounds__(256) void k_cpb_bias(const float* __restrict__ tbl,
    float* __restrict__ biasA){
  int idx = blockIdx.x*256 + threadIdx.x;
  if (idx >= 6*64*64) return;
  int h = idx >> 12, n = (idx >> 6) & 63, m = idx & 63;
  int dh = (n>>3) - (m>>3) + 7, dw = (n&7) - (m&7) + 7;
  float v = tbl[(dh*15 + dw)*6 + h];
  biasA[idx] = 16.f / (1.f + expf(-v));
}

// ---------------- merged weight prep (all packs + cvtpads + cb pack) ---------
DEV void pack_one(int idx, const float* __restrict__ src,
                  unsigned short* __restrict__ dst, int Ncols, int K, int KS){
  int j = idx & 7, l = (idx >> 3) & 63, f = idx >> 9;
  int ks = f - (f/KS)*KS, ct = f/KS;
  int col = ct*16 + (l & 15);
  int k = ks*32 + (l >> 4)*8 + j;
  float v = (col < Ncols && k < K) ? src[col*K + k] : 0.f;
  dst[idx] = f2b(v);
}

DEV void cvt_one(int idx, const float* __restrict__ src,
                 unsigned short* __restrict__ dst, int R, int K, int Kp){
  int r = idx / Kp, k = idx - r*Kp;
  float v = (r < R && k < K) ? src[r*K + k] : 0.f;
  dst[idx] = f2b(v);
}

DEV void packcb_one(int idx, const float* __restrict__ cbw,
                    unsigned short* __restrict__ dst){
  int j = idx & 7, l = (idx >> 3) & 63, f = idx >> 9;
  int k0 = f % 3; f /= 3;
  int cc = f % 6; f /= 6;
  int tap = f % 9; int g = f/9;
  int col = cc*16 + (l & 15);
  int k = k0*32 + (l >> 4)*8 + j;
  float v = (col < 90 && k < 90) ? cbw[((g*90 + col)*90 + k)*9 + tap] : 0.f;
  dst[idx] = f2b(v);
}

__global__ __launch_bounds__(256) void k_prep(
    const float* __restrict__ qkv_w, const float* __restrict__ proj_w,
    const float* __restrict__ pew,   const float* __restrict__ fc1w,
    const float* __restrict__ fc2w,  const float* __restrict__ p1w,
    const float* __restrict__ pww,   const float* __restrict__ p2w,
    const float* __restrict__ cbw,
    unsigned short* __restrict__ wqp,  unsigned short* __restrict__ wpjp,
    unsigned short* __restrict__ wpep, unsigned short* __restrict__ wf1p,
    unsigned short* __restrict__ wf2p, unsigned short* __restrict__ wp1,
    unsigned short* __restrict__ wpw,  unsigned short* __restrict__ wp2,
    unsigned short* __restrict__ wcbp){
  int idx = blockIdx.x*256 + threadIdx.x;
  if (idx < 104448) { pack_one(idx, qkv_w, wqp, 540, 180, 6); return; }
  idx -= 104448;
  if (idx < 36864)  { pack_one(idx, proj_w, wpjp, 180, 180, 6); return; }
  idx -= 36864;
  if (idx < 36864)  { pack_one(idx, pew, wpep, 180, 180, 6); return; }
  idx -= 36864;
  if (idx < 138240) { pack_one(idx, fc1w, wf1p, 720, 180, 6); return; }
  idx -= 138240;
  if (idx < 141312) { pack_one(idx, fc2w, wf2p, 180, 720, 23); return; }
  idx -= 141312;
  if (idx < 18432)  { cvt_one(idx, p1w, wp1, 96, 180, 192); return; }
  idx -= 18432;
  if (idx < 9216)   { cvt_one(idx, pww, wpw, 96, 96, 96); return; }
  idx -= 9216;
  if (idx < 18432)  { cvt_one(idx, p2w, wp2, 180, 96, 96); return; }
  idx -= 18432;
  if (idx < 165888) { packcb_one(idx, cbw, wcbp); return; }
}

// ---- fused qkv GEMM + window attention + proj + norm1 -> x1 (1024 thr) -----
__global__ __launch_bounds__(1024) void k_qa_mfma(const float* __restrict__ x,
    const unsigned short* __restrict__ wqp, const float* __restrict__ qb,
    const float* __restrict__ vb, const float* __restrict__ biasA,
    const float* __restrict__ lsc,
    const unsigned short* __restrict__ wpjp, const float* __restrict__ pb,
    const float* __restrict__ g1, const float* __restrict__ b1,
    float* __restrict__ x1){
  __shared__ __align__(16) unsigned short SH[73728];
  __shared__ int rowOff[64];
  float* invq = (float*)(SH + 72192);
  float* invk = (float*)(SH + 72960);
  int win = blockIdx.x, tid = threadIdx.x;
  if (tid < 64) {
    int b = win/144, rem = win - b*144, wh = rem/12, ww = rem - (rem/12)*12;
    int l = (wh*8 + (tid>>3))*96 + ww*8 + (tid&7);
    rowOff[tid] = (b*9216 + l)*180;
  }
  __syncthreads();
  for (int idx = tid; idx < 64*45; idx += 1024) {
    int i = idx/45, k4 = idx - i*45;
    float4 v = *(const float4*)(x + rowOff[i] + k4*4);
    pack4(SH + i*200 + k4*4, v);
  }
  for (int idx = tid; idx < 64*12; idx += 1024) {
    int i = idx/12, k = idx - (idx/12)*12;
    SH[i*200 + 180 + k] = 0;
  }
  __syncthreads();
  int wid = tid>>6, lane = tid&63, lr = lane&15, lg = lane>>4;
  f4v z = {0.f,0.f,0.f,0.f};
  for (int ct = wid; ct < 34; ct += 16) {
    f4v acc[4];
    #pragma unroll
    for (int rg = 0; rg < 4; ++rg) acc[rg] = z;
    #pragma unroll
    for (int k0 = 0; k0 < 6; ++k0) {
      s8v b = *(const s8v*)(wqp + (size_t)((ct*6 + k0)*64 + lane)*8);
      #pragma unroll
      for (int rg = 0; rg < 4; ++rg) {
        s8v a = *(const s8v*)(SH + (16*rg + lr)*200 + k0*32 + lg*8);
        acc[rg] = mfma16(a, b, acc[rg]);
      }
    }
    int c = ct*16 + lr;
    if (c < 540) {
      float bias = qkvbias(c, qb, vb);
      int base, d, isV = 0;
      if (c < 180)      { int h = c/30;        d = c - h*30;        base = 27648 + h*2560; }
      else if (c < 360) { int h = (c-180)/30;  d = (c-180) - h*30;  base = 43008 + h*2560; }
      else              { int h = (c-360)/30;  d = (c-360) - h*30;  base = 58368 + h*2304; isV = 1; }
      #pragma unroll
      for (int rg = 0; rg < 4; ++rg)
        #pragma unroll
        for (int i = 0; i < 4; ++i) {
          int n = 16*rg + lg*4 + i;
          int addr = isV ? (base + d*72 + n) : (base + n*40 + d);
          SH[addr] = f2b(acc[rg][i] + bias);
        }
    }
  }
  __syncthreads();
  for (int j = tid; j < 1536; j += 1024) {
    int tensor = j >= 768;
    int rem = j - tensor*768;
    int h = rem >> 7, r2 = rem & 127;
    int n = r2 >> 1, d = 30 + (r2 & 1);
    SH[(tensor ? 43008 : 27648) + h*2560 + n*40 + d] = 0;
  }
  for (int j = tid; j < 864; j += 1024) {
    int h = j/144, rem = j - h*144;
    int d = 30 + rem/72, m = rem - (rem/72)*72;
    SH[58368 + h*2304 + d*72 + m] = 0;
  }
  for (int j = tid; j < 768; j += 1024) {
    int tensor = j >= 384;
    int rem = j - tensor*384;
    const unsigned short* basep = SH + (tensor ? 43008 : 27648)
                                     + (rem >> 6)*2560 + (rem & 63)*40;
    float s = 0.f;
    for (int d = 0; d < 30; ++d) { float v = b2f(basep[d]); s += v*v; }
    float inv = 1.f / fmaxf(sqrtf(s), 1e-12f);
    (tensor ? invk : invq)[rem] = inv;
  }
  __syncthreads();
  f4v oa0[2], oa1[2];
  #pragma unroll
  for (int tt = 0; tt < 2; ++tt) {
    int t = wid + tt*16;
    if (t < 24) {
      int h = t >> 2, rb = t & 3;
      float scale = __expf(fminf(lsc[h], 4.6051701859880914f));
      const unsigned short* Qh = SH + 27648 + h*2560;
      const unsigned short* Kh = SH + 43008 + h*2560;
      const unsigned short* Vh = SH + 58368 + h*2304;
      unsigned short* Ph = SH + h*4608;
      s8v aq = *(const s8v*)(Qh + (16*rb + lr)*40 + lg*8);
      f4v sacc[4];
      #pragma unroll
      for (int tc = 0; tc < 4; ++tc) {
        s8v bk = *(const s8v*)(Kh + (16*tc + lr)*40 + lg*8);
        sacc[tc] = mfma16(aq, bk, z);
      }
      float iq[4], ikv[4];
      #pragma unroll
      for (int i = 0; i < 4; ++i) iq[i] = invq[h*64 + 16*rb + lg*4 + i] * scale;
      #pragma unroll
      for (int tc = 0; tc < 4; ++tc) ikv[tc] = invk[h*64 + 16*tc + lr];
      float p[4][4];
      #pragma unroll
      for (int tc = 0; tc < 4; ++tc) {
        int col = 16*tc + lr;
        #pragma unroll
        for (int i = 0; i < 4; ++i) {
          int row = 16*rb + lg*4 + i;
          p[tc][i] = sacc[tc][i]*iq[i]*ikv[tc] + biasA[((h*64 + row) << 6) + col];
        }
      }
      float rin[4];
      #pragma unroll
      for (int i = 0; i < 4; ++i) {
        float mx = fmaxf(fmaxf(p[0][i], p[1][i]), fmaxf(p[2][i], p[3][i]));
        mx = rmax16(mx);
        float sum = 0.f;
        #pragma unroll
        for (int tc = 0; tc < 4; ++tc) { p[tc][i] = __expf(p[tc][i] - mx); sum += p[tc][i]; }
        sum = rsum16(sum);
        rin[i] = 1.f / sum;
      }
      #pragma unroll
      for (int tc = 0; tc < 4; ++tc)
        #pragma unroll
        for (int i = 0; i < 4; ++i)
          Ph[(16*rb + lg*4 + i)*72 + 16*tc + lr] = f2b(p[tc][i]*rin[i]);
      f4v o0 = z, o1 = z;
      #pragma unroll
      for (int k0 = 0; k0 < 2; ++k0) {
        s8v pa = *(const s8v*)(Ph + (16*rb + lr)*72 + k0*32 + lg*8);
        s8v b0 = *(const s8v*)(Vh + lr*72        + k0*32 + lg*8);
        s8v b1 = *(const s8v*)(Vh + (16 + lr)*72 + k0*32 + lg*8);
        o0 = mfma16(pa, b0, o0);
        o1 = mfma16(pa, b1, o1);
      }
      oa0[tt] = o0; oa1[tt] = o1;
    }
  }
  __syncthreads();
  unsigned short* Aw = SH + 43008;
  #pragma unroll
  for (int tt = 0; tt < 2; ++tt) {
    int t = wid + tt*16;
    if (t < 24) {
      int h = t >> 2, rb = t & 3;
      #pragma unroll
      for (int i = 0; i < 4; ++i) {
        int row = 16*rb + lg*4 + i;
        Aw[row*200 + h*30 + lr] = f2b(oa0[tt][i]);
        int c1 = 16 + lr;
        if (c1 < 30) Aw[row*200 + h*30 + c1] = f2b(oa1[tt][i]);
      }
    }
  }
  for (int idx = tid; idx < 64*12; idx += 1024) {
    int r = idx/12, j = idx - (idx/12)*12;
    Aw[r*200 + 180 + j] = 0;
  }
  __syncthreads();
  float* redS = (float*)(SH + 58368);
  float* redQ = (float*)(SH + 58368 + 1536*4);
  f4v pacc[4];
  #pragma unroll
  for (int rg = 0; rg < 4; ++rg) pacc[rg] = z;
  if (wid < 12) {
    #pragma unroll
    for (int k0 = 0; k0 < 6; ++k0) {
      s8v b = *(const s8v*)(wpjp + (size_t)((wid*6 + k0)*64 + lane)*8);
      #pragma unroll
      for (int rg = 0; rg < 4; ++rg) {
        s8v a = *(const s8v*)(Aw + (16*rg + lr)*200 + k0*32 + lg*8);
        pacc[rg] = mfma16(a, b, pacc[rg]);
      }
    }
  }
  float psum[4][4], psq[4][4];
  #pragma unroll
  for (int rg = 0; rg < 4; ++rg)
    #pragma unroll
    for (int i = 0; i < 4; ++i) { psum[rg][i] = 0.f; psq[rg][i] = 0.f; }
  if (wid < 12) {
    int c = wid*16 + lr;
    float bv = (c < 180) ? pb[c] : 0.f;
    #pragma unroll
    for (int rg = 0; rg < 4; ++rg)
      #pragma unroll
      for (int i = 0; i < 4; ++i) {
        float v = (c < 180) ? pacc[rg][i] + bv : 0.f;
        pacc[rg][i] = v;
        psum[rg][i] += v; psq[rg][i] += v*v;
      }
  }
  #pragma unroll
  for (int rg = 0; rg < 4; ++rg)
    #pragma unroll
    for (int i = 0; i < 4; ++i) {
      psum[rg][i] = rsum16(psum[rg][i]);
      psq[rg][i]  = rsum16(psq[rg][i]);
    }
  if (lr == 0 && wid < 12) {
    #pragma unroll
    for (int rg = 0; rg < 4; ++rg)
      #pragma unroll
      for (int i = 0; i < 4; ++i) {
        int row = 16*rg + lg*4 + i;
        redS[wid*64 + row] = psum[rg][i];
        redQ[wid*64 + row] = psq[rg][i];
      }
  }
  __syncthreads();
  #pragma unroll
  for (int rg = 0; rg < 4; ++rg)
    #pragma unroll
    for (int i = 0; i < 4; ++i) {
      int row = 16*rg + lg*4 + i;
      float s = 0.f, s2 = 0.f;
      #pragma unroll
      for (int w = 0; w < 12; ++w) { s += redS[w*64 + row]; s2 += redQ[w*64 + row]; }
      float m = s*(1.f/180.f);
      float var = fmaxf(s2*(1.f/180.f) - m*m, 0.f);
      float rs = rsqrtf(var + 1e-5f);
      if (wid < 12) {
        int c = wid*16 + lr;
        if (c < 180) {
          size_t o = (size_t)rowOff[row] + c;
          x1[o] = x[o] + (pacc[rg][i] - m)*rs*g1[c] + b1[c];
        }
      }
    }
}

// ---------------- fused VAB p1 + pw: x1 -> v1 (f32, global) and ab1 ----------
__global__ __launch_bounds__(256) void k_p1w_mfma(const float* __restrict__ x1,
    const unsigned short* __restrict__ wp1, const float* __restrict__ b1p,
    float* __restrict__ v1,
    const unsigned short* __restrict__ wpw, const float* __restrict__ bpw,
    float* __restrict__ ab1){
  __shared__ __align__(16) unsigned short A[64*200];
  __shared__ __align__(16) unsigned short A2[64*104];
  int blk = blockIdx.x, tid = threadIdx.x;
  int b = blk/144, p0 = (blk - b*144)*64;
  int rowb = b*9216 + p0;
  for (int idx = tid; idx < 64*45; idx += 256) {
    int i = idx/45, k4 = idx - i*45;
    float4 v = *(const float4*)(x1 + (size_t)(rowb + i)*180 + k4*4);
    pack4(A + i*200 + k4*4, v);
  }
  for (int idx = tid; idx < 64*12; idx += 256) {
    int i = idx/12, k = idx - (idx/12)*12;
    A[i*200 + 180 + k] = 0;
  }
  __syncthreads();
  int wid = tid>>6, lane = tid&63, lr = lane&15, lg = lane>>4;
  const unsigned short* arow = A + (16*wid + lr)*200 + lg*8;
  f4v z = {0.f,0.f,0.f,0.f};
  #pragma unroll
  for (int pp = 0; pp < 3; ++pp) {
    int c0 = pp*32;
    f4v acc0 = z, acc1 = z;
    #pragma unroll
    for (int k0 = 0; k0 < 6; ++k0) {
      s8v a  = *(const s8v*)(arow + k0*32);
      s8v b0 = *(const s8v*)(wp1 + (size_t)(c0 + lr)*192 + k0*32 + lg*8);
      s8v b1 = *(const s8v*)(wp1 + (size_t)(c0 + 16 + lr)*192 + k0*32 + lg*8);
      acc0 = mfma16(a, b0, acc0);
      acc1 = mfma16(a, b1, acc1);
    }
    int c  = c0 + lr, c2 = c0 + 16 + lr;
    float bv = b1p[c], bv2 = b1p[c2];
    #pragma unroll
    for (int i = 0; i < 4; ++i) {
      int px = 16*wid + lg*4 + i;
      float g0 = geluf(acc0[i] + bv );
      float g1 = geluf(acc1[i] + bv2);
      v1[(size_t)(b*96 + c )*9216 + p0 + px] = g0;
      v1[(size_t)(b*96 + c2)*9216 + p0 + px] = g1;
      A2[px*104 + c ] = f2b(g0);
      A2[px*104 + c2] = f2b(g1);
    }
  }
  __syncthreads();
  const unsigned short* arow2 = A2 + (16*wid + lr)*104 + lg*8;
  #pragma unroll
  for (int pp = 0; pp < 3; ++pp) {
    int c0 = pp*32;
    f4v acc0 = z, acc1 = z;
    #pragma unroll
    for (int k0 = 0; k0 < 3; ++k0) {
      s8v a  = *(const s8v*)(arow2 + k0*32);
      s8v b0 = *(const s8v*)(wpw + (size_t)(c0 + lr)*96 + k0*32 + lg*8);
      s8v b1 = *(const s8v*)(wpw + (size_t)(c0 + 16 + lr)*96 + k0*32 + lg*8);
      acc0 = mfma16(a, b0, acc0);
      acc1 = mfma16(a, b1, acc1);
    }
    int c  = c0 + lr, c2 = c0 + 16 + lr;
    float bv = bpw[c], bv2 = bpw[c2];
    #pragma unroll
    for (int i = 0; i < 4; ++i) {
      int px = 16*wid + lg*4 + i;
      ab1[(size_t)(b*96 + c )*9216 + p0 + px] = acc0[i] + bv;
      ab1[(size_t)(b*96 + c2)*9216 + p0 + px] = acc1[i] + bv2;
    }
  }
}

// ---------------- depthwise 5x5 pair, half-plane split w/ halo: ab1 -> ab2 ---
__global__ __launch_bounds__(512) void k_dwcf(const float* __restrict__ ab1,
    float* __restrict__ ab2,
    const float* __restrict__ w1, const float* __restrict__ b1,
    const float* __restrict__ w2, const float* __restrict__ b2){
  __shared__ float P0[56*96];
  __shared__ float P1[54*96];
  int blk = blockIdx.x;
  int bc = blk >> 1, half = blk & 1;     // bc = b*96 + c
  int c = bc - (bc/96)*96;
  int tid = threadIdx.x;
  int h0 = half*48;
  int r0p = half ? 40 : 0;               // P0 rows [r0p, r0p+56)
  int r0q = half ? 42 : 0;               // P1 rows [r0q, r0q+54)
  const float* gp = ab1 + (size_t)bc*9216;
  float* go = ab2 + (size_t)bc*9216;
  const float4* src4 = (const float4*)(gp + r0p*96);
  for (int i = tid; i < 56*24; i += 512)
    ((float4*)P0)[i] = src4[i];
  __syncthreads();
  const float* wc1 = w1 + c*25;
  float bv1 = b1[c];
  for (int idx = tid; idx < 54*96; idx += 512) {
    int y = r0q + idx/96, xx0 = idx - (idx/96)*96;
    float acc = bv1;
    #pragma unroll
    for (int i = 0; i < 5; ++i) {
      int yy = y + (i-2);
      if (yy < 0 || yy >= 96) continue;
      const float* row = P0 + (yy - r0p)*96;
      #pragma unroll
      for (int j = 0; j < 5; ++j) {
        int xq = xx0 + (j-2);
        if (xq >= 0 && xq < 96) acc += row[xq]*wc1[i*5 + j];
      }
    }
    P1[(y - r0q)*96 + xx0] = acc;
  }
  __syncthreads();
  const float* wc2 = w2 + c*25;
  float bv2 = b2[c];
  for (int idx = tid; idx < 48*96; idx += 512) {
    int y = h0 + idx/96, xx0 = idx - (idx/96)*96;
    float acc = bv2;
    #pragma unroll
    for (int i = 0; i < 5; ++i) {
      int yy = y + 3*(i-2);
      if (yy < 0 || yy >= 96) continue;
      const float* row = P1 + (yy - r0q)*96;
      #pragma unroll
      for (int j = 0; j < 5; ++j) {
        int xq = xx0 + 3*(j-2);
        if (xq >= 0 && xq < 96) acc += row[xq]*wc2[i*5 + j];
      }
    }
    go[y*96 + xx0] = acc;
  }
}

// ---------------- p2 + residual + VAB-LN -> vnb NHWC bf16 (group-padded) -----
__global__ __launch_bounds__(256) void k_p2ln_mfma(const float* __restrict__ v1,
    const float* __restrict__ a3, const float* __restrict__ x1,
    const unsigned short* __restrict__ wp2, const float* __restrict__ bias,
    const float* __restrict__ lng, const float* __restrict__ lnb,
    unsigned short* __restrict__ vnb){
  __shared__ unsigned short A[64*104];
  int blk = blockIdx.x, tid = threadIdx.x;
  int b = blk/144, p0 = (blk - b*144)*64;
  for (int idx = tid; idx < 96*16; idx += 256) {
    int k = idx >> 4, i4 = (idx & 15)*4;
    size_t o = (size_t)(b*96 + k)*9216 + p0 + i4;
    float4 va = *(const float4*)(v1 + o);
    float4 vb = *(const float4*)(a3 + o);
    A[(i4+0)*104 + k] = f2b(va.x*vb.x);
    A[(i4+1)*104 + k] = f2b(va.y*vb.y);
    A[(i4+2)*104 + k] = f2b(va.z*vb.z);
    A[(i4+3)*104 + k] = f2b(va.w*vb.w);
  }
  __syncthreads();
  int wid = tid>>6, lane = tid&63, lr = lane&15, lg = lane>>4;
  const unsigned short* arow = A + (16*wid + lr)*104 + lg*8;
  f4v z = {0.f,0.f,0.f,0.f};
  f4v acc[12];
  #pragma unroll
  for (int cc = 0; cc < 12; ++cc) acc[cc] = z;
  #pragma unroll
  for (int k0 = 0; k0 < 3; ++k0) {
    s8v a = *(const s8v*)(arow + k0*32);
    #pragma unroll
    for (int cc = 0; cc < 12; ++cc) {
      s8v bb = *(const s8v*)(wp2 + (size_t)(cc*16 + lr)*96 + k0*32 + lg*8);
      acc[cc] = mfma16(a, bb, acc[cc]);
    }
  }
  float psum[4] = {0,0,0,0}, psq[4] = {0,0,0,0};
  #pragma unroll
  for (int cc = 0; cc < 12; ++cc) {
    int c = cc*16 + lr;
    float bv = (c < 180) ? bias[c] : 0.f;
    #pragma unroll
    for (int i = 0; i < 4; ++i) {
      int px = 16*wid + lg*4 + i;
      float v = 0.f;
      if (c < 180) v = acc[cc][i] + bv + x1[(size_t)(b*9216 + p0 + px)*180 + c];
      acc[cc][i] = v;
      psum[i] += v; psq[i] += v*v;
    }
  }
  float m[4], rs[4];
  #pragma unroll
  for (int i = 0; i < 4; ++i) {
    float s = rsum16(psum[i]), s2 = rsum16(psq[i]);
    m[i] = s*(1.f/180.f);
    float var = fmaxf(s2*(1.f/180.f) - m[i]*m[i], 0.f);
    rs[i] = rsqrtf(var + 1e-5f);
  }
  #pragma unroll
  for (int cc = 0; cc < 12; ++cc) {
    int c = cc*16 + lr;
    if (c < 180) {
      int cpos = c + (c >= 90 ? 6 : 0);
      #pragma unroll
      for (int i = 0; i < 4; ++i) {
        int px = 16*wid + lg*4 + i;
        vnb[(size_t)(b*9216 + p0 + px)*192 + cpos] =
            f2b((acc[cc][i] - m[i])*rs[i]*lng[c] + lnb[c]);
      }
    }
  }
  for (int idx = tid; idx < 64*12; idx += 256) {
    int px = idx/12, j = idx - (idx/12)*12;
    int pos = (j < 6) ? (90 + j) : (180 + j);
    vnb[(size_t)(b*9216 + p0 + px)*192 + pos] = 0;
  }
}

// ---------------- convbody: 8x8 tile, halo once, wave-owns-(g,cc3), packed B -
__global__ __launch_bounds__(256) void k_cb_mfma(const unsigned short* __restrict__ vnb,
    const unsigned short* __restrict__ wcbp, const float* __restrict__ bias,
    unsigned short* __restrict__ cbn){
  __shared__ __align__(16) unsigned short S[100*200];   // 10x10 halo x 192ch, stride 200
  int blk = blockIdx.x, tid = threadIdx.x;
  int b = blk/144, t = blk - b*144;
  int th = t/12, tw = t - (t/12)*12;
  int h0 = th*8, w0 = tw*8;
  for (int idx = tid; idx < 2400; idx += 256) {
    int pix = idx/24, chunk = idx - pix*24;
    int hp = pix/10, wp = pix - hp*10;
    int h = h0 + hp - 1, w = w0 + wp - 1;
    s8v v = {0,0,0,0,0,0,0,0};
    if (h >= 0 && h < 96 && w >= 0 && w < 96)
      v = *(const s8v*)(vnb + (size_t)(b*9216 + h*96 + w)*192 + chunk*8);
    *(s8v*)(S + pix*200 + chunk*8) = v;
  }
  __syncthreads();
  int wid = tid>>6, lane = tid&63, lr = lane&15, lg = lane>>4;
  int g = wid >> 1, ccb = (wid & 1)*3;
  f4v z = {0.f,0.f,0.f,0.f};
  f4v acc[3][4];
  #pragma unroll
  for (int t3 = 0; t3 < 3; ++t3)
    #pragma unroll
    for (int rg = 0; rg < 4; ++rg) acc[t3][rg] = z;
  #pragma unroll
  for (int tap = 0; tap < 9; ++tap) {
    int dh = tap/3 - 1, dw = tap - (tap/3)*3 - 1;
    #pragma unroll
    for (int k0 = 0; k0 < 3; ++k0) {
      s8v a0, a1, a2, a3;
      {
        int base_k = g*96 + k0*32 + lg*8;
        int ai0 = lr;
        a0 = *(const s8v*)(S + (((ai0>>3)+1+dh)*10 + (ai0&7)+1+dw)*200 + base_k);
        int ai1 = 16 + lr;
        a1 = *(const s8v*)(S + (((ai1>>3)+1+dh)*10 + (ai1&7)+1+dw)*200 + base_k);
        int ai2 = 32 + lr;
        a2 = *(const s8v*)(S + (((ai2>>3)+1+dh)*10 + (ai2&7)+1+dw)*200 + base_k);
        int ai3 = 48 + lr;
        a3 = *(const s8v*)(S + (((ai3>>3)+1+dh)*10 + (ai3&7)+1+dw)*200 + base_k);
      }
      #pragma unroll
      for (int t3 = 0; t3 < 3; ++t3) {
        int cc = ccb + t3;
        s8v bb = *(const s8v*)(wcbp + (size_t)((((g*9 + tap)*6 + cc)*3 + k0)*64 + lane)*8);
        acc[t3][0] = mfma16(a0, bb, acc[t3][0]);
        acc[t3][1] = mfma16(a1, bb, acc[t3][1]);
        acc[t3][2] = mfma16(a2, bb, acc[t3][2]);
        acc[t3][3] = mfma16(a3, bb, acc[t3][3]);
      }
    }
  }
  #pragma unroll
  for (int t3 = 0; t3 < 3; ++t3) {
    int c = (ccb + t3)*16 + lr;
    if (c < 90) {
      int o = g*90 + c;
      float bv = bias[o];
      #pragma unroll
      for (int rg = 0; rg < 4; ++rg)
        #pragma unroll
        for (int i = 0; i < 4; ++i) {
          int oi = 16*rg + lg*4 + i;
          int oy = oi>>3, ox = oi&7;
          cbn[(size_t)(b*9216 + (h0+oy)*96 + (w0+ox))*192 + o] = f2b(acc[t3][rg][i] + bv);
        }
    }
  }
  for (int idx = tid; idx < 64*12; idx += 256) {
    int pxi = idx/12, j = idx - (idx/12)*12;
    int oy = pxi>>3, ox = pxi&7;
    cbn[(size_t)(b*9216 + (h0+oy)*96 + (w0+ox))*192 + 180 + j] = 0;
  }
}

// ---- fused pe + MLP (1024 thr, reg-resident pe-val, single outp write) -----
__global__ __launch_bounds__(1024) void k_pef_mfma(const unsigned short* __restrict__ cbn,
    const unsigned short* __restrict__ wpep, const float* __restrict__ peb,
    const float* __restrict__ x1, float* __restrict__ outp,
    const unsigned short* __restrict__ wf1p, const float* __restrict__ b1f,
    const unsigned short* __restrict__ wf2p, const float* __restrict__ fcb2,
    const float* __restrict__ g2, const float* __restrict__ b2ln){
  __shared__ __align__(16) unsigned short A[64*200];
  __shared__ __align__(16) unsigned short Hs[64*744];
  __shared__ float redS[12][64], redQ[12][64];
  int blk = blockIdx.x, tid = threadIdx.x;
  int b = blk/144, p0 = (blk - b*144)*64;
  size_t r0 = (size_t)(b*9216 + p0);
  for (int idx = tid; idx < 64*24; idx += 1024) {
    int i = idx/24, ch = idx - i*24;
    *(s8v*)(A + i*200 + ch*8) = *(const s8v*)(cbn + (r0 + i)*192 + ch*8);
  }
  __syncthreads();
  int wid = tid>>6, lane = tid&63, lr = lane&15, lg = lane>>4;
  f4v z = {0.f,0.f,0.f,0.f};
  // ---- pe GEMM: one ct per wave (waves 0..11 active); val kept in regs ----
  f4v pval[4];
  #pragma unroll
  for (int rg = 0; rg < 4; ++rg) pval[rg] = z;
  if (wid < 12) {
    #pragma unroll
    for (int k0 = 0; k0 < 6; ++k0) {
      s8v bb = *(const s8v*)(wpep + (size_t)((wid*6 + k0)*64 + lane)*8);
      #pragma unroll
      for (int rg = 0; rg < 4; ++rg) {
        s8v a = *(const s8v*)(A + (16*rg + lr)*200 + k0*32 + lg*8);
        pval[rg] = mfma16(a, bb, pval[rg]);
      }
    }
  }
  __syncthreads();   // A reads done; A becomes pe-out staging (bf16 val)
  if (wid < 12) {
    int c = wid*16 + lr;
    if (c < 180) {
      float bv = peb[c];
      #pragma unroll
      for (int rg = 0; rg < 4; ++rg)
        #pragma unroll
        for (int i = 0; i < 4; ++i) {
          int row = 16*rg + lg*4 + i;
          size_t o = (r0 + row)*180 + c;
          float val = x1[o] + pval[rg][i] + bv;
          pval[rg][i] = val;             // stays in registers until final write
          A[row*200 + c] = f2b(val);
        }
    }
  }
  for (int idx = tid; idx < 64*20; idx += 1024) {
    int r = idx/20, j = idx - (idx/20)*20;
    A[r*200 + 180 + j] = 0;
  }
  __syncthreads();
  // ---- fc1: 45 ct over 16 waves (3 rounds) ----
  for (int ct = wid; ct < 45; ct += 16) {
    f4v acc[4];
    #pragma unroll
    for (int rg = 0; rg < 4; ++rg) acc[rg] = z;
    #pragma unroll
    for (int k0 = 0; k0 < 6; ++k0) {
      s8v bb = *(const s8v*)(wf1p + (size_t)((ct*6 + k0)*64 + lane)*8);
      #pragma unroll
      for (int rg = 0; rg < 4; ++rg) {
        s8v a = *(const s8v*)(A + (16*rg + lr)*200 + k0*32 + lg*8);
        acc[rg] = mfma16(a, bb, acc[rg]);
      }
    }
    int c = ct*16 + lr;
    float bv = b1f[c];
    #pragma unroll
    for (int rg = 0; rg < 4; ++rg)
      #pragma unroll
      for (int i = 0; i < 4; ++i)
        Hs[(16*rg + lg*4 + i)*744 + c] = f2b(geluf(acc[rg][i] + bv));
  }
  for (int idx = tid; idx < 64*16; idx += 1024) {
    int r = idx >> 4, j = idx & 15;
    Hs[r*744 + 720 + j] = 0;
  }
  __syncthreads();
  // ---- fc2: wave wid<12 owns ct=wid over all 4 row-groups (pe-aligned) ----
  f4v acc2[4];
  #pragma unroll
  for (int rg = 0; rg < 4; ++rg) acc2[rg] = z;
  if (wid < 12) {
    for (int ks = 0; ks < 23; ++ks) {
      s8v bb = *(const s8v*)(wf2p + (size_t)((wid*23 + ks)*64 + lane)*8);
      #pragma unroll
      for (int rg = 0; rg < 4; ++rg) {
        s8v a0 = *(const s8v*)(Hs + (16*rg + lr)*744 + ks*32 + lg*8);
        acc2[rg] = mfma16(a0, bb, acc2[rg]);
      }
    }
  }
  float psum[4][4], psq[4][4];
  #pragma unroll
  for (int rg = 0; rg < 4; ++rg)
    #pragma unroll
    for (int i = 0; i < 4; ++i) { psum[rg][i] = 0.f; psq[rg][i] = 0.f; }
  if (wid < 12) {
    int c = wid*16 + lr;
    float bv = (c < 180) ? fcb2[c] : 0.f;
    #pragma unroll
    for (int rg = 0; rg < 4; ++rg)
      #pragma unroll
      for (int i = 0; i < 4; ++i) {
        float v = (c < 180) ? acc2[rg][i] + bv : 0.f;
        acc2[rg][i] = v;
        psum[rg][i] += v; psq[rg][i] += v*v;
      }
  }
  #pragma unroll
  for (int rg = 0; rg < 4; ++rg)
    #pragma unroll
    for (int i = 0; i < 4; ++i) {
      psum[rg][i] = rsum16(psum[rg][i]);
      psq[rg][i]  = rsum16(psq[rg][i]);
    }
  if (lr == 0 && wid < 12) {
    #pragma unroll
    for (int rg = 0; rg < 4; ++rg)
      #pragma unroll
      for (int i = 0; i < 4; ++i) {
        int row = 16*rg + lg*4 + i;
        redS[wid][row] = psum[rg][i];
        redQ[wid][row] = psq[rg][i];
      }
  }
  __syncthreads();
  #pragma unroll
  for (int rg = 0; rg < 4; ++rg)
    #pragma unroll
    for (int i = 0; i < 4; ++i) {
      int row = 16*rg + lg*4 + i;
      float s = 0.f, s2 = 0.f;
      #pragma unroll
      for (int w = 0; w < 12; ++w) { s += redS[w][row]; s2 += redQ[w][row]; }
      float m = s*(1.f/180.f);
      float var = fmaxf(s2*(1.f/180.f) - m*m, 0.f);
      float rs = rsqrtf(var + 1e-5f);
      if (wid < 12) {
        int c = wid*16 + lr;
        if (c < 180) {
          size_t o = (r0 + row)*180 + c;
          outp[o] = pval[rg][i] + (acc2[rg][i] - m)*rs*g2[c] + b2ln[c];
        }
      }
    }
}

// ---------------- launch ----------------
extern "C" void kernel_launch(void* const* d_in, const int* in_sizes, int n_in,
                              void* d_out, int out_size, void* d_ws, size_t ws_size,
                              hipStream_t stream) {
  const float* x      = (const float*)d_in[0];
  const float* qkv_w  = (const float*)d_in[1];
  const float* q_bias = (const float*)d_in[2];
  const float* v_bias = (const float*)d_in[3];
  const float* lsc    = (const float*)d_in[4];
  const float* cpb_w1 = (const float*)d_in[5];
  const float* cpb_b1 = (const float*)d_in[6];
  const float* cpb_w2 = (const float*)d_in[7];
  const float* proj_w = (const float*)d_in[8];
  const float* proj_b = (const float*)d_in[9];
  const float* n1g    = (const float*)d_in[10];
  const float* n1b    = (const float*)d_in[11];
  const float* n2g    = (const float*)d_in[12];
  const float* n2b    = (const float*)d_in[13];
  const float* fc1w   = (const float*)d_in[14];
  const float* fc1b   = (const float*)d_in[15];
  const float* fc2w   = (const float*)d_in[16];
  const float* fc2b   = (const float*)d_in[17];
  const float* p1w    = (const float*)d_in[18];
  const float* p1b    = (const float*)d_in[19];
  const float* pww    = (const float*)d_in[20];
  const float* pwb    = (const float*)d_in[21];
  const float* dww    = (const float*)d_in[22];
  const float* dwb    = (const float*)d_in[23];
  const float* ddw    = (const float*)d_in[24];
  const float* ddb    = (const float*)d_in[25];
  const float* p2w    = (const float*)d_in[26];
  const float* p2b    = (const float*)d_in[27];
  const float* vlng   = (const float*)d_in[28];
  const float* vlnb   = (const float*)d_in[29];
  const float* cbw    = (const float*)d_in[30];
  const float* cbb    = (const float*)d_in[31];
  const float* pew    = (const float*)d_in[32];
  const float* peb    = (const float*)d_in[33];
  float* out = (float*)d_out;
  char* ws = (char*)d_ws;

  float* x1   = (float*)(ws + OFF_X1);
  float* v1   = (float*)(ws + OFF_V1);
  float* ab1  = (float*)(ws + OFF_AB1);
  float* ab2  = (float*)(ws + OFF_AB2);
  unsigned short* vnb = (unsigned short*)(ws + OFF_VNB);
  unsigned short* cbn = (unsigned short*)(ws + OFF_CBN);
  float* tbl   = (float*)(ws + O_TBL);
  float* biasA = (float*)(ws + O_BIASA);
  unsigned short* wqp = (unsigned short*)(ws + O_WQ);
  unsigned short* wpjp = (unsigned short*)(ws + O_WPJ);
  unsigned short* wpep = (unsigned short*)(ws + O_WPE);
  unsigned short* wp1 = (unsigned short*)(ws + O_WP1);
  unsigned short* wpw = (unsigned short*)(ws + O_WPW);
  unsigned short* wp2 = (unsigned short*)(ws + O_WP2);
  unsigned short* wf1p = (unsigned short*)(ws + O_WF1);
  unsigned short* wf2p = (unsigned short*)(ws + O_WF2);
  unsigned short* wcbp = (unsigned short*)(ws + O_WCB);

  // prep (3 launches)
  k_cpb_tbl<<<225, 512, 0, stream>>>(cpb_w1, cpb_b1, cpb_w2, tbl);
  k_cpb_bias<<<96, 256, 0, stream>>>(tbl, biasA);
  k_prep<<<(669696 + 255)/256, 256, 0, stream>>>(qkv_w, proj_w, pew, fc1w, fc2w,
      p1w, pww, p2w, cbw, wqp, wpjp, wpep, wf1p, wf2p, wp1, wpw, wp2, wcbp);
  // main chain
  k_qa_mfma<<<NWIN, 1024, 0, stream>>>(x, wqp, q_bias, v_bias, biasA, lsc,
                                       wpjp, proj_b, n1g, n1b, x1);
  k_p1w_mfma<<<NWIN, 256, 0, stream>>>(x1, wp1, p1b, v1, wpw, pwb, ab1);
  k_dwcf<<<1536, 512, 0, stream>>>(ab1, ab2, dww, dwb, ddw, ddb);
  k_p2ln_mfma<<<NWIN, 256, 0, stream>>>(v1, ab2, x1, wp2, p2b, vlng, vlnb, vnb);
  k_cb_mfma<<<NWIN, 256, 0, stream>>>(vnb, wcbp, cbb, cbn);
  k_pef_mfma<<<NWIN, 1024, 0, stream>>>(cbn, wpep, peb, x1, out,
                                        wf1p, fc1b, wf2p, fc2b, n2g, n2b);
}

// Round 27
// 536.560 us; speedup vs baseline: 1.0080x; 1.0080x over previous
//
#include <hip/hip_runtime.h>
#include <hip/hip_bf16.h>

#define DEV __device__ __forceinline__

typedef __attribute__((ext_vector_type(8))) short s8v;   // 8 bf16 (4 VGPR)
typedef __attribute__((ext_vector_type(4))) float f4v;   // MFMA acc

static constexpr int NWIN = 1152;
static constexpr int NROW = 73728;

// ---------------- workspace layout (peak < 185.8 MB) ----
static constexpr size_t OFF_X1   = 132710400;    // f32  [NROW][180]  (live until pe/p2)
static constexpr size_t OFF_V1   = 0;            // f32  NCHW [8*96][9216]
static constexpr size_t OFF_AB1  = 28311552;     // f32  NCHW
static constexpr size_t OFF_AB2  = 84934656;     // f32  NCHW (dwcf output, no in-place race)
static constexpr size_t OFF_VNB  = 56623104;     // bf16 NHWC [NROW][192] — group-padded layout
static constexpr size_t OFF_CBN  = 0;            // bf16 NHWC [NROW][192] (over v1, dead)
static constexpr size_t WB       = 130613248;
static constexpr size_t O_TBL    = WB;                    // f32 [225][6]
static constexpr size_t O_BIASA  = WB + 8192;             // f32 [6][64][64]
static constexpr size_t O_WQ     = WB + 106496;           // bf16 packed frag-major [34*6*512]
static constexpr size_t O_WPJ    = O_WQ  + 208896;        // bf16 packed frag-major [12*6*512]
static constexpr size_t O_WPE    = O_WPJ + 73728;         // bf16 packed frag-major [12*6*512]
static constexpr size_t O_WP1    = O_WPE + 73728;         // bf16 [96][192]
static constexpr size_t O_WPW    = O_WP1 + 36864;         // bf16 [96][96]
static constexpr size_t O_WP2    = O_WPW + 18432;         // bf16 [192][96]
static constexpr size_t O_WF1    = O_WP2 + 36864;         // bf16 packed frag-major [45*6*512]
static constexpr size_t O_WF2    = O_WF1 + 282624;        // bf16 packed frag-major [12*23*512]
static constexpr size_t O_WCB    = O_WF2 + 282624;        // bf16 packed frag-major [2*9*6*3*512]

DEV float geluf(float x){ return 0.5f*x*(1.f + erff(x*0.70710678118654752f)); }

DEV unsigned short f2b(float v){
  union { __hip_bfloat16 h; unsigned short u; } x;
  x.h = __float2bfloat16(v);
  return x.u;
}

DEV float b2f(unsigned short u){
  union { float f; unsigned u; } x;
  x.u = ((unsigned)u) << 16;
  return x.f;
}

DEV f4v mfma16(s8v a, s8v b, f4v c){
  return __builtin_amdgcn_mfma_f32_16x16x32_bf16(a, b, c, 0, 0, 0);
}

DEV float rsum16(float v){
  v += __shfl_xor(v, 1); v += __shfl_xor(v, 2);
  v += __shfl_xor(v, 4); v += __shfl_xor(v, 8);
  return v;
}

DEV float rmax16(float v){
  v = fmaxf(v, __shfl_xor(v, 1)); v = fmaxf(v, __shfl_xor(v, 2));
  v = fmaxf(v, __shfl_xor(v, 4)); v = fmaxf(v, __shfl_xor(v, 8));
  return v;
}

DEV float qkvbias(int c, const float* qb, const float* vb){
  return (c < 180) ? qb[c] : (c < 360 ? 0.f : vb[c-360]);
}

DEV void pack4(unsigned short* dst, float4 v){
  unsigned p0 = (unsigned)f2b(v.x) | ((unsigned)f2b(v.y) << 16);
  unsigned p1 = (unsigned)f2b(v.z) | ((unsigned)f2b(v.w) << 16);
  uint2 pk; pk.x = p0; pk.y = p1;
  *(uint2*)dst = pk;
}

// ---------------- CPB MLP table ----------------
__global__ __launch_bounds__(512) void k_cpb_tbl(const float* __restrict__ w1,
    const float* __restrict__ b1, const float* __restrict__ w2, float* __restrict__ tbl){
  int m = blockIdx.x, tid = threadIdx.x;
  int i = m/15, j = m - (m/15)*15;
  float t0 = (float)(i-7)*(8.f/7.f), t1 = (float)(j-7)*(8.f/7.f);
  float f0 = log2f(fabsf(t0)+1.f)*(1.f/3.f); if (t0 < 0.f) f0 = -f0;
  float f1 = log2f(fabsf(t1)+1.f)*(1.f/3.f); if (t1 < 0.f) f1 = -f1;
  float hv = fmaxf(f0*w1[2*tid] + f1*w1[2*tid+1] + b1[tid], 0.f);
  __shared__ float red[6][8];
  int lane = tid & 63, wv = tid >> 6;
  for (int h = 0; h < 6; ++h) {
    float p = hv * w2[h*512 + tid];
    for (int off = 32; off; off >>= 1) p += __shfl_down(p, off);
    if (lane == 0) red[h][wv] = p;
  }
  __syncthreads();
  if (tid < 6) {
    float s = 0.f;
    for (int w = 0; w < 8; ++w) s += red[tid][w];
    tbl[m*6 + tid] = s;
  }
}

__global__ __launch_bounds__(256) void k_cpb_bias(const float* __restrict__ tbl,
    float* __restrict__ biasA){
  int idx = blockIdx.x*256 + threadIdx.x;
  if (idx >= 6*64*64) return;
  int h = idx >> 12, n = (idx >> 6) & 63, m = idx & 63;
  int dh = (n>>3) - (m>>3) + 7, dw = (n&7) - (m&7) + 7;
  float v = tbl[(dh*15 + dw)*6 + h];
  biasA[idx] = 16.f / (1.f + expf(-v));
}

// ---------------- merged weight prep (all packs + cvtpads + cb pack) ---------
DEV void pack_one(int idx, const float* __restrict__ src,
                  unsigned short* __restrict__ dst, int Ncols, int K, int KS){
  int j = idx & 7, l = (idx >> 3) & 63, f = idx >> 9;
  int ks = f - (f/KS)*KS, ct = f/KS;
  int col = ct*16 + (l & 15);
  int k = ks*32 + (l >> 4)*8 + j;
  float v = (col < Ncols && k < K) ? src[col*K + k] : 0.f;
  dst[idx] = f2b(v);
}

DEV void cvt_one(int idx, const float* __restrict__ src,
                 unsigned short* __restrict__ dst, int R, int K, int Kp){
  int r = idx / Kp, k = idx - r*Kp;
  float v = (r < R && k < K) ? src[r*K + k] : 0.f;
  dst[idx] = f2b(v);
}

DEV void packcb_one(int idx, const float* __restrict__ cbw,
                    unsigned short* __restrict__ dst){
  int j = idx & 7, l = (idx >> 3) & 63, f = idx >> 9;
  int k0 = f % 3; f /= 3;
  int cc = f % 6; f /= 6;
  int tap = f % 9; int g = f/9;
  int col = cc*16 + (l & 15);
  int k = k0*32 + (l >> 4)*8 + j;
  float v = (col < 90 && k < 90) ? cbw[((g*90 + col)*90 + k)*9 + tap] : 0.f;
  dst[idx] = f2b(v);
}

__global__ __launch_bounds__(256) void k_prep(
    const float* __restrict__ qkv_w, const float* __restrict__ proj_w,
    const float* __restrict__ pew,   const float* __restrict__ fc1w,
    const float* __restrict__ fc2w,  const float* __restrict__ p1w,
    const float* __restrict__ pww,   const float* __restrict__ p2w,
    const float* __restrict__ cbw,
    unsigned short* __restrict__ wqp,  unsigned short* __restrict__ wpjp,
    unsigned short* __restrict__ wpep, unsigned short* __restrict__ wf1p,
    unsigned short* __restrict__ wf2p, unsigned short* __restrict__ wp1,
    unsigned short* __restrict__ wpw,  unsigned short* __restrict__ wp2,
    unsigned short* __restrict__ wcbp){
  int idx = blockIdx.x*256 + threadIdx.x;
  if (idx < 104448) { pack_one(idx, qkv_w, wqp, 540, 180, 6); return; }
  idx -= 104448;
  if (idx < 36864)  { pack_one(idx, proj_w, wpjp, 180, 180, 6); return; }
  idx -= 36864;
  if (idx < 36864)  { pack_one(idx, pew, wpep, 180, 180, 6); return; }
  idx -= 36864;
  if (idx < 138240) { pack_one(idx, fc1w, wf1p, 720, 180, 6); return; }
  idx -= 138240;
  if (idx < 141312) { pack_one(idx, fc2w, wf2p, 180, 720, 23); return; }
  idx -= 141312;
  if (idx < 18432)  { cvt_one(idx, p1w, wp1, 96, 180, 192); return; }
  idx -= 18432;
  if (idx < 9216)   { cvt_one(idx, pww, wpw, 96, 96, 96); return; }
  idx -= 9216;
  if (idx < 18432)  { cvt_one(idx, p2w, wp2, 180, 96, 96); return; }
  idx -= 18432;
  if (idx < 165888) { packcb_one(idx, cbw, wcbp); return; }
}

// ---- fused qkv GEMM + window attention + proj + norm1 -> x1 (1024 thr) -----
__global__ __launch_bounds__(1024) void k_qa_mfma(const float* __restrict__ x,
    const unsigned short* __restrict__ wqp, const float* __restrict__ qb,
    const float* __restrict__ vb, const float* __restrict__ biasA,
    const float* __restrict__ lsc,
    const unsigned short* __restrict__ wpjp, const float* __restrict__ pb,
    const float* __restrict__ g1, const float* __restrict__ b1,
    float* __restrict__ x1){
  __shared__ __align__(16) unsigned short SH[73728];
  __shared__ int rowOff[64];
  float* invq = (float*)(SH + 72192);
  float* invk = (float*)(SH + 72960);
  int win = blockIdx.x, tid = threadIdx.x;
  if (tid < 64) {
    int b = win/144, rem = win - b*144, wh = rem/12, ww = rem - (rem/12)*12;
    int l = (wh*8 + (tid>>3))*96 + ww*8 + (tid&7);
    rowOff[tid] = (b*9216 + l)*180;
  }
  __syncthreads();
  for (int idx = tid; idx < 64*45; idx += 1024) {
    int i = idx/45, k4 = idx - i*45;
    float4 v = *(const float4*)(x + rowOff[i] + k4*4);
    pack4(SH + i*200 + k4*4, v);
  }
  for (int idx = tid; idx < 64*12; idx += 1024) {
    int i = idx/12, k = idx - (idx/12)*12;
    SH[i*200 + 180 + k] = 0;
  }
  __syncthreads();
  int wid = tid>>6, lane = tid&63, lr = lane&15, lg = lane>>4;
  f4v z = {0.f,0.f,0.f,0.f};
  for (int ct = wid; ct < 34; ct += 16) {
    f4v acc[4];
    #pragma unroll
    for (int rg = 0; rg < 4; ++rg) acc[rg] = z;
    #pragma unroll
    for (int k0 = 0; k0 < 6; ++k0) {
      s8v b = *(const s8v*)(wqp + (size_t)((ct*6 + k0)*64 + lane)*8);
      #pragma unroll
      for (int rg = 0; rg < 4; ++rg) {
        s8v a = *(const s8v*)(SH + (16*rg + lr)*200 + k0*32 + lg*8);
        acc[rg] = mfma16(a, b, acc[rg]);
      }
    }
    int c = ct*16 + lr;
    if (c < 540) {
      float bias = qkvbias(c, qb, vb);
      int base, d, isV = 0;
      if (c < 180)      { int h = c/30;        d = c - h*30;        base = 27648 + h*2560; }
      else if (c < 360) { int h = (c-180)/30;  d = (c-180) - h*30;  base = 43008 + h*2560; }
      else              { int h = (c-360)/30;  d = (c-360) - h*30;  base = 58368 + h*2304; isV = 1; }
      #pragma unroll
      for (int rg = 0; rg < 4; ++rg)
        #pragma unroll
        for (int i = 0; i < 4; ++i) {
          int n = 16*rg + lg*4 + i;
          int addr = isV ? (base + d*72 + n) : (base + n*40 + d);
          SH[addr] = f2b(acc[rg][i] + bias);
        }
    }
  }
  __syncthreads();
  for (int j = tid; j < 1536; j += 1024) {
    int tensor = j >= 768;
    int rem = j - tensor*768;
    int h = rem >> 7, r2 = rem & 127;
    int n = r2 >> 1, d = 30 + (r2 & 1);
    SH[(tensor ? 43008 : 27648) + h*2560 + n*40 + d] = 0;
  }
  for (int j = tid; j < 864; j += 1024) {
    int h = j/144, rem = j - h*144;
    int d = 30 + rem/72, m = rem - (rem/72)*72;
    SH[58368 + h*2304 + d*72 + m] = 0;
  }
  for (int j = tid; j < 768; j += 1024) {
    int tensor = j >= 384;
    int rem = j - tensor*384;
    const unsigned short* basep = SH + (tensor ? 43008 : 27648)
                                     + (rem >> 6)*2560 + (rem & 63)*40;
    float s = 0.f;
    for (int d = 0; d < 30; ++d) { float v = b2f(basep[d]); s += v*v; }
    float inv = 1.f / fmaxf(sqrtf(s), 1e-12f);
    (tensor ? invk : invq)[rem] = inv;
  }
  __syncthreads();
  f4v oa0[2], oa1[2];
  #pragma unroll
  for (int tt = 0; tt < 2; ++tt) {
    int t = wid + tt*16;
    if (t < 24) {
      int h = t >> 2, rb = t & 3;
      float scale = __expf(fminf(lsc[h], 4.6051701859880914f));
      const unsigned short* Qh = SH + 27648 + h*2560;
      const unsigned short* Kh = SH + 43008 + h*2560;
      const unsigned short* Vh = SH + 58368 + h*2304;
      unsigned short* Ph = SH + h*4608;
      s8v aq = *(const s8v*)(Qh + (16*rb + lr)*40 + lg*8);
      f4v sacc[4];
      #pragma unroll
      for (int tc = 0; tc < 4; ++tc) {
        s8v bk = *(const s8v*)(Kh + (16*tc + lr)*40 + lg*8);
        sacc[tc] = mfma16(aq, bk, z);
      }
      float iq[4], ikv[4];
      #pragma unroll
      for (int i = 0; i < 4; ++i) iq[i] = invq[h*64 + 16*rb + lg*4 + i] * scale;
      #pragma unroll
      for (int tc = 0; tc < 4; ++tc) ikv[tc] = invk[h*64 + 16*tc + lr];
      float p[4][4];
      #pragma unroll
      for (int tc = 0; tc < 4; ++tc) {
        int col = 16*tc + lr;
        #pragma unroll
        for (int i = 0; i < 4; ++i) {
          int row = 16*rb + lg*4 + i;
          p[tc][i] = sacc[tc][i]*iq[i]*ikv[tc] + biasA[((h*64 + row) << 6) + col];
        }
      }
      float rin[4];
      #pragma unroll
      for (int i = 0; i < 4; ++i) {
        float mx = fmaxf(fmaxf(p[0][i], p[1][i]), fmaxf(p[2][i], p[3][i]));
        mx = rmax16(mx);
        float sum = 0.f;
        #pragma unroll
        for (int tc = 0; tc < 4; ++tc) { p[tc][i] = __expf(p[tc][i] - mx); sum += p[tc][i]; }
        sum = rsum16(sum);
        rin[i] = 1.f / sum;
      }
      #pragma unroll
      for (int tc = 0; tc < 4; ++tc)
        #pragma unroll
        for (int i = 0; i < 4; ++i)
          Ph[(16*rb + lg*4 + i)*72 + 16*tc + lr] = f2b(p[tc][i]*rin[i]);
      f4v o0 = z, o1 = z;
      #pragma unroll
      for (int k0 = 0; k0 < 2; ++k0) {
        s8v pa = *(const s8v*)(Ph + (16*rb + lr)*72 + k0*32 + lg*8);
        s8v b0 = *(const s8v*)(Vh + lr*72        + k0*32 + lg*8);
        s8v b1 = *(const s8v*)(Vh + (16 + lr)*72 + k0*32 + lg*8);
        o0 = mfma16(pa, b0, o0);
        o1 = mfma16(pa, b1, o1);
      }
      oa0[tt] = o0; oa1[tt] = o1;
    }
  }
  __syncthreads();
  unsigned short* Aw = SH + 43008;
  #pragma unroll
  for (int tt = 0; tt < 2; ++tt) {
    int t = wid + tt*16;
    if (t < 24) {
      int h = t >> 2, rb = t & 3;
      #pragma unroll
      for (int i = 0; i < 4; ++i) {
        int row = 16*rb + lg*4 + i;
        Aw[row*200 + h*30 + lr] = f2b(oa0[tt][i]);
        int c1 = 16 + lr;
        if (c1 < 30) Aw[row*200 + h*30 + c1] = f2b(oa1[tt][i]);
      }
    }
  }
  for (int idx = tid; idx < 64*12; idx += 1024) {
    int r = idx/12, j = idx - (idx/12)*12;
    Aw[r*200 + 180 + j] = 0;
  }
  __syncthreads();
  float* redS = (float*)(SH + 58368);
  float* redQ = (float*)(SH + 58368 + 1536*4);
  f4v pacc[4];
  #pragma unroll
  for (int rg = 0; rg < 4; ++rg) pacc[rg] = z;
  if (wid < 12) {
    #pragma unroll
    for (int k0 = 0; k0 < 6; ++k0) {
      s8v b = *(const s8v*)(wpjp + (size_t)((wid*6 + k0)*64 + lane)*8);
      #pragma unroll
      for (int rg = 0; rg < 4; ++rg) {
        s8v a = *(const s8v*)(Aw + (16*rg + lr)*200 + k0*32 + lg*8);
        pacc[rg] = mfma16(a, b, pacc[rg]);
      }
    }
  }
  float psum[4][4], psq[4][4];
  #pragma unroll
  for (int rg = 0; rg < 4; ++rg)
    #pragma unroll
    for (int i = 0; i < 4; ++i) { psum[rg][i] = 0.f; psq[rg][i] = 0.f; }
  if (wid < 12) {
    int c = wid*16 + lr;
    float bv = (c < 180) ? pb[c] : 0.f;
    #pragma unroll
    for (int rg = 0; rg < 4; ++rg)
      #pragma unroll
      for (int i = 0; i < 4; ++i) {
        float v = (c < 180) ? pacc[rg][i] + bv : 0.f;
        pacc[rg][i] = v;
        psum[rg][i] += v; psq[rg][i] += v*v;
      }
  }
  #pragma unroll
  for (int rg = 0; rg < 4; ++rg)
    #pragma unroll
    for (int i = 0; i < 4; ++i) {
      psum[rg][i] = rsum16(psum[rg][i]);
      psq[rg][i]  = rsum16(psq[rg][i]);
    }
  if (lr == 0 && wid < 12) {
    #pragma unroll
    for (int rg = 0; rg < 4; ++rg)
      #pragma unroll
      for (int i = 0; i < 4; ++i) {
        int row = 16*rg + lg*4 + i;
        redS[wid*64 + row] = psum[rg][i];
        redQ[wid*64 + row] = psq[rg][i];
      }
  }
  __syncthreads();
  #pragma unroll
  for (int rg = 0; rg < 4; ++rg)
    #pragma unroll
    for (int i = 0; i < 4; ++i) {
      int row = 16*rg + lg*4 + i;
      float s = 0.f, s2 = 0.f;
      #pragma unroll
      for (int w = 0; w < 12; ++w) { s += redS[w*64 + row]; s2 += redQ[w*64 + row]; }
      float m = s*(1.f/180.f);
      float var = fmaxf(s2*(1.f/180.f) - m*m, 0.f);
      float rs = rsqrtf(var + 1e-5f);
      if (wid < 12) {
        int c = wid*16 + lr;
        if (c < 180) {
          size_t o = (size_t)rowOff[row] + c;
          x1[o] = x[o] + (pacc[rg][i] - m)*rs*g1[c] + b1[c];
        }
      }
    }
}

// ---------------- fused VAB p1 + pw: x1 -> v1 (f32, global) and ab1 ----------
__global__ __launch_bounds__(256) void k_p1w_mfma(const float* __restrict__ x1,
    const unsigned short* __restrict__ wp1, const float* __restrict__ b1p,
    float* __restrict__ v1,
    const unsigned short* __restrict__ wpw, const float* __restrict__ bpw,
    float* __restrict__ ab1){
  __shared__ __align__(16) unsigned short A[64*200];
  __shared__ __align__(16) unsigned short A2[64*104];
  int blk = blockIdx.x, tid = threadIdx.x;
  int b = blk/144, p0 = (blk - b*144)*64;
  int rowb = b*9216 + p0;
  for (int idx = tid; idx < 64*45; idx += 256) {
    int i = idx/45, k4 = idx - i*45;
    float4 v = *(const float4*)(x1 + (size_t)(rowb + i)*180 + k4*4);
    pack4(A + i*200 + k4*4, v);
  }
  for (int idx = tid; idx < 64*12; idx += 256) {
    int i = idx/12, k = idx - (idx/12)*12;
    A[i*200 + 180 + k] = 0;
  }
  __syncthreads();
  int wid = tid>>6, lane = tid&63, lr = lane&15, lg = lane>>4;
  const unsigned short* arow = A + (16*wid + lr)*200 + lg*8;
  f4v z = {0.f,0.f,0.f,0.f};
  #pragma unroll
  for (int pp = 0; pp < 3; ++pp) {
    int c0 = pp*32;
    f4v acc0 = z, acc1 = z;
    #pragma unroll
    for (int k0 = 0; k0 < 6; ++k0) {
      s8v a  = *(const s8v*)(arow + k0*32);
      s8v b0 = *(const s8v*)(wp1 + (size_t)(c0 + lr)*192 + k0*32 + lg*8);
      s8v b1 = *(const s8v*)(wp1 + (size_t)(c0 + 16 + lr)*192 + k0*32 + lg*8);
      acc0 = mfma16(a, b0, acc0);
      acc1 = mfma16(a, b1, acc1);
    }
    int c  = c0 + lr, c2 = c0 + 16 + lr;
    float bv = b1p[c], bv2 = b1p[c2];
    #pragma unroll
    for (int i = 0; i < 4; ++i) {
      int px = 16*wid + lg*4 + i;
      float g0 = geluf(acc0[i] + bv );
      float g1 = geluf(acc1[i] + bv2);
      v1[(size_t)(b*96 + c )*9216 + p0 + px] = g0;
      v1[(size_t)(b*96 + c2)*9216 + p0 + px] = g1;
      A2[px*104 + c ] = f2b(g0);
      A2[px*104 + c2] = f2b(g1);
    }
  }
  __syncthreads();
  const unsigned short* arow2 = A2 + (16*wid + lr)*104 + lg*8;
  #pragma unroll
  for (int pp = 0; pp < 3; ++pp) {
    int c0 = pp*32;
    f4v acc0 = z, acc1 = z;
    #pragma unroll
    for (int k0 = 0; k0 < 3; ++k0) {
      s8v a  = *(const s8v*)(arow2 + k0*32);
      s8v b0 = *(const s8v*)(wpw + (size_t)(c0 + lr)*96 + k0*32 + lg*8);
      s8v b1 = *(const s8v*)(wpw + (size_t)(c0 + 16 + lr)*96 + k0*32 + lg*8);
      acc0 = mfma16(a, b0, acc0);
      acc1 = mfma16(a, b1, acc1);
    }
    int c  = c0 + lr, c2 = c0 + 16 + lr;
    float bv = bpw[c], bv2 = bpw[c2];
    #pragma unroll
    for (int i = 0; i < 4; ++i) {
      int px = 16*wid + lg*4 + i;
      ab1[(size_t)(b*96 + c )*9216 + p0 + px] = acc0[i] + bv;
      ab1[(size_t)(b*96 + c2)*9216 + p0 + px] = acc1[i] + bv2;
    }
  }
}

// ---------------- depthwise 5x5 pair, half-plane split w/ halo: ab1 -> ab2 ---
__global__ __launch_bounds__(512) void k_dwcf(const float* __restrict__ ab1,
    float* __restrict__ ab2,
    const float* __restrict__ w1, const float* __restrict__ b1,
    const float* __restrict__ w2, const float* __restrict__ b2){
  __shared__ float P0[56*96];
  __shared__ float P1[54*96];
  int blk = blockIdx.x;
  int bc = blk >> 1, half = blk & 1;     // bc = b*96 + c
  int c = bc - (bc/96)*96;
  int tid = threadIdx.x;
  int h0 = half*48;
  int r0p = half ? 40 : 0;               // P0 rows [r0p, r0p+56)
  int r0q = half ? 42 : 0;               // P1 rows [r0q, r0q+54)
  const float* gp = ab1 + (size_t)bc*9216;
  float* go = ab2 + (size_t)bc*9216;
  const float4* src4 = (const float4*)(gp + r0p*96);
  for (int i = tid; i < 56*24; i += 512)
    ((float4*)P0)[i] = src4[i];
  __syncthreads();
  const float* wc1 = w1 + c*25;
  float bv1 = b1[c];
  for (int idx = tid; idx < 54*96; idx += 512) {
    int y = r0q + idx/96, xx0 = idx - (idx/96)*96;
    float acc = bv1;
    #pragma unroll
    for (int i = 0; i < 5; ++i) {
      int yy = y + (i-2);
      if (yy < 0 || yy >= 96) continue;
      const float* row = P0 + (yy - r0p)*96;
      #pragma unroll
      for (int j = 0; j < 5; ++j) {
        int xq = xx0 + (j-2);
        if (xq >= 0 && xq < 96) acc += row[xq]*wc1[i*5 + j];
      }
    }
    P1[(y - r0q)*96 + xx0] = acc;
  }
  __syncthreads();
  const float* wc2 = w2 + c*25;
  float bv2 = b2[c];
  for (int idx = tid; idx < 48*96; idx += 512) {
    int y = h0 + idx/96, xx0 = idx - (idx/96)*96;
    float acc = bv2;
    #pragma unroll
    for (int i = 0; i < 5; ++i) {
      int yy = y + 3*(i-2);
      if (yy < 0 || yy >= 96) continue;
      const float* row = P1 + (yy - r0q)*96;
      #pragma unroll
      for (int j = 0; j < 5; ++j) {
        int xq = xx0 + 3*(j-2);
        if (xq >= 0 && xq < 96) acc += row[xq]*wc2[i*5 + j];
      }
    }
    go[y*96 + xx0] = acc;
  }
}

// ---------------- p2 + residual + VAB-LN -> vnb NHWC bf16 (group-padded) -----
__global__ __launch_bounds__(256) void k_p2ln_mfma(const float* __restrict__ v1,
    const float* __restrict__ a3, const float* __restrict__ x1,
    const unsigned short* __restrict__ wp2, const float* __restrict__ bias,
    const float* __restrict__ lng, const float* __restrict__ lnb,
    unsigned short* __restrict__ vnb){
  __shared__ unsigned short A[64*104];
  int blk = blockIdx.x, tid = threadIdx.x;
  int b = blk/144, p0 = (blk - b*144)*64;
  for (int idx = tid; idx < 96*16; idx += 256) {
    int k = idx >> 4, i4 = (idx & 15)*4;
    size_t o = (size_t)(b*96 + k)*9216 + p0 + i4;
    float4 va = *(const float4*)(v1 + o);
    float4 vb = *(const float4*)(a3 + o);
    A[(i4+0)*104 + k] = f2b(va.x*vb.x);
    A[(i4+1)*104 + k] = f2b(va.y*vb.y);
    A[(i4+2)*104 + k] = f2b(va.z*vb.z);
    A[(i4+3)*104 + k] = f2b(va.w*vb.w);
  }
  __syncthreads();
  int wid = tid>>6, lane = tid&63, lr = lane&15, lg = lane>>4;
  const unsigned short* arow = A + (16*wid + lr)*104 + lg*8;
  f4v z = {0.f,0.f,0.f,0.f};
  f4v acc[12];
  #pragma unroll
  for (int cc = 0; cc < 12; ++cc) acc[cc] = z;
  #pragma unroll
  for (int k0 = 0; k0 < 3; ++k0) {
    s8v a = *(const s8v*)(arow + k0*32);
    #pragma unroll
    for (int cc = 0; cc < 12; ++cc) {
      s8v bb = *(const s8v*)(wp2 + (size_t)(cc*16 + lr)*96 + k0*32 + lg*8);
      acc[cc] = mfma16(a, bb, acc[cc]);
    }
  }
  float psum[4] = {0,0,0,0}, psq[4] = {0,0,0,0};
  #pragma unroll
  for (int cc = 0; cc < 12; ++cc) {
    int c = cc*16 + lr;
    float bv = (c < 180) ? bias[c] : 0.f;
    #pragma unroll
    for (int i = 0; i < 4; ++i) {
      int px = 16*wid + lg*4 + i;
      float v = 0.f;
      if (c < 180) v = acc[cc][i] + bv + x1[(size_t)(b*9216 + p0 + px)*180 + c];
      acc[cc][i] = v;
      psum[i] += v; psq[i] += v*v;
    }
  }
  float m[4], rs[4];
  #pragma unroll
  for (int i = 0; i < 4; ++i) {
    float s = rsum16(psum[i]), s2 = rsum16(psq[i]);
    m[i] = s*(1.f/180.f);
    float var = fmaxf(s2*(1.f/180.f) - m[i]*m[i], 0.f);
    rs[i] = rsqrtf(var + 1e-5f);
  }
  #pragma unroll
  for (int cc = 0; cc < 12; ++cc) {
    int c = cc*16 + lr;
    if (c < 180) {
      int cpos = c + (c >= 90 ? 6 : 0);
      #pragma unroll
      for (int i = 0; i < 4; ++i) {
        int px = 16*wid + lg*4 + i;
        vnb[(size_t)(b*9216 + p0 + px)*192 + cpos] =
            f2b((acc[cc][i] - m[i])*rs[i]*lng[c] + lnb[c]);
      }
    }
  }
  for (int idx = tid; idx < 64*12; idx += 256) {
    int px = idx/12, j = idx - (idx/12)*12;
    int pos = (j < 6) ? (90 + j) : (180 + j);
    vnb[(size_t)(b*9216 + p0 + px)*192 + pos] = 0;
  }
}

// ---------------- convbody: 8x8 tile, halo once, wave-owns-(g,cc3), packed B -
__global__ __launch_bounds__(256) void k_cb_mfma(const unsigned short* __restrict__ vnb,
    const unsigned short* __restrict__ wcbp, const float* __restrict__ bias,
    unsigned short* __restrict__ cbn){
  __shared__ __align__(16) unsigned short S[100*200];   // 10x10 halo x 192ch, stride 200
  int blk = blockIdx.x, tid = threadIdx.x;
  int b = blk/144, t = blk - b*144;
  int th = t/12, tw = t - (t/12)*12;
  int h0 = th*8, w0 = tw*8;
  for (int idx = tid; idx < 2400; idx += 256) {
    int pix = idx/24, chunk = idx - pix*24;
    int hp = pix/10, wp = pix - hp*10;
    int h = h0 + hp - 1, w = w0 + wp - 1;
    s8v v = {0,0,0,0,0,0,0,0};
    if (h >= 0 && h < 96 && w >= 0 && w < 96)
      v = *(const s8v*)(vnb + (size_t)(b*9216 + h*96 + w)*192 + chunk*8);
    *(s8v*)(S + pix*200 + chunk*8) = v;
  }
  __syncthreads();
  int wid = tid>>6, lane = tid&63, lr = lane&15, lg = lane>>4;
  int g = wid >> 1, ccb = (wid & 1)*3;
  f4v z = {0.f,0.f,0.f,0.f};
  f4v acc[3][4];
  #pragma unroll
  for (int t3 = 0; t3 < 3; ++t3)
    #pragma unroll
    for (int rg = 0; rg < 4; ++rg) acc[t3][rg] = z;
  #pragma unroll
  for (int tap = 0; tap < 9; ++tap) {
    int dh = tap/3 - 1, dw = tap - (tap/3)*3 - 1;
    #pragma unroll
    for (int k0 = 0; k0 < 3; ++k0) {
      s8v a0, a1, a2, a3;
      {
        int base_k = g*96 + k0*32 + lg*8;
        int ai0 = lr;
        a0 = *(const s8v*)(S + (((ai0>>3)+1+dh)*10 + (ai0&7)+1+dw)*200 + base_k);
        int ai1 = 16 + lr;
        a1 = *(const s8v*)(S + (((ai1>>3)+1+dh)*10 + (ai1&7)+1+dw)*200 + base_k);
        int ai2 = 32 + lr;
        a2 = *(const s8v*)(S + (((ai2>>3)+1+dh)*10 + (ai2&7)+1+dw)*200 + base_k);
        int ai3 = 48 + lr;
        a3 = *(const s8v*)(S + (((ai3>>3)+1+dh)*10 + (ai3&7)+1+dw)*200 + base_k);
      }
      #pragma unroll
      for (int t3 = 0; t3 < 3; ++t3) {
        int cc = ccb + t3;
        s8v bb = *(const s8v*)(wcbp + (size_t)((((g*9 + tap)*6 + cc)*3 + k0)*64 + lane)*8);
        acc[t3][0] = mfma16(a0, bb, acc[t3][0]);
        acc[t3][1] = mfma16(a1, bb, acc[t3][1]);
        acc[t3][2] = mfma16(a2, bb, acc[t3][2]);
        acc[t3][3] = mfma16(a3, bb, acc[t3][3]);
      }
    }
  }
  #pragma unroll
  for (int t3 = 0; t3 < 3; ++t3) {
    int c = (ccb + t3)*16 + lr;
    if (c < 90) {
      int o = g*90 + c;
      float bv = bias[o];
      #pragma unroll
      for (int rg = 0; rg < 4; ++rg)
        #pragma unroll
        for (int i = 0; i < 4; ++i) {
          int oi = 16*rg + lg*4 + i;
          int oy = oi>>3, ox = oi&7;
          cbn[(size_t)(b*9216 + (h0+oy)*96 + (w0+ox))*192 + o] = f2b(acc[t3][rg][i] + bv);
        }
    }
  }
  for (int idx = tid; idx < 64*12; idx += 256) {
    int pxi = idx/12, j = idx - (idx/12)*12;
    int oy = pxi>>3, ox = pxi&7;
    cbn[(size_t)(b*9216 + (h0+oy)*96 + (w0+ox))*192 + 180 + j] = 0;
  }
}

// ---- fused pe + MLP (1024 thr, 4 waves/EU, reg-resident pe-val) ------------
__global__ __launch_bounds__(1024, 4) void k_pef_mfma(const unsigned short* __restrict__ cbn,
    const unsigned short* __restrict__ wpep, const float* __restrict__ peb,
    const float* __restrict__ x1, float* __restrict__ outp,
    const unsigned short* __restrict__ wf1p, const float* __restrict__ b1f,
    const unsigned short* __restrict__ wf2p, const float* __restrict__ fcb2,
    const float* __restrict__ g2, const float* __restrict__ b2ln){
  __shared__ __align__(16) unsigned short A[64*200];
  __shared__ __align__(16) unsigned short Hs[64*744];
  __shared__ float redS[12][64], redQ[12][64];
  int blk = blockIdx.x, tid = threadIdx.x;
  int b = blk/144, p0 = (blk - b*144)*64;
  size_t r0 = (size_t)(b*9216 + p0);
  for (int idx = tid; idx < 64*24; idx += 1024) {
    int i = idx/24, ch = idx - i*24;
    *(s8v*)(A + i*200 + ch*8) = *(const s8v*)(cbn + (r0 + i)*192 + ch*8);
  }
  __syncthreads();
  int wid = tid>>6, lane = tid&63, lr = lane&15, lg = lane>>4;
  f4v z = {0.f,0.f,0.f,0.f};
  // ---- pe GEMM: one ct per wave (waves 0..11 active); val kept in regs ----
  f4v pval[4];
  #pragma unroll
  for (int rg = 0; rg < 4; ++rg) pval[rg] = z;
  if (wid < 12) {
    #pragma unroll
    for (int k0 = 0; k0 < 6; ++k0) {
      s8v bb = *(const s8v*)(wpep + (size_t)((wid*6 + k0)*64 + lane)*8);
      #pragma unroll
      for (int rg = 0; rg < 4; ++rg) {
        s8v a = *(const s8v*)(A + (16*rg + lr)*200 + k0*32 + lg*8);
        pval[rg] = mfma16(a, bb, pval[rg]);
      }
    }
  }
  __syncthreads();   // A reads done; A becomes pe-out staging (bf16 val)
  if (wid < 12) {
    int c = wid*16 + lr;
    if (c < 180) {
      float bv = peb[c];
      #pragma unroll
      for (int rg = 0; rg < 4; ++rg)
        #pragma unroll
        for (int i = 0; i < 4; ++i) {
          int row = 16*rg + lg*4 + i;
          size_t o = (r0 + row)*180 + c;
          float val = x1[o] + pval[rg][i] + bv;
          pval[rg][i] = val;             // stays in registers until final write
          A[row*200 + c] = f2b(val);
        }
    }
  }
  for (int idx = tid; idx < 64*20; idx += 1024) {
    int r = idx/20, j = idx - (idx/20)*20;
    A[r*200 + 180 + j] = 0;
  }
  __syncthreads();
  // ---- fc1: 45 ct over 16 waves (3 rounds) ----
  for (int ct = wid; ct < 45; ct += 16) {
    f4v acc[4];
    #pragma unroll
    for (int rg = 0; rg < 4; ++rg) acc[rg] = z;
    #pragma unroll
    for (int k0 = 0; k0 < 6; ++k0) {
      s8v bb = *(const s8v*)(wf1p + (size_t)((ct*6 + k0)*64 + lane)*8);
      #pragma unroll
      for (int rg = 0; rg < 4; ++rg) {
        s8v a = *(const s8v*)(A + (16*rg + lr)*200 + k0*32 + lg*8);
        acc[rg] = mfma16(a, bb, acc[rg]);
      }
    }
    int c = ct*16 + lr;
    float bv = b1f[c];
    #pragma unroll
    for (int rg = 0; rg < 4; ++rg)
      #pragma unroll
      for (int i = 0; i < 4; ++i)
        Hs[(16*rg + lg*4 + i)*744 + c] = f2b(geluf(acc[rg][i] + bv));
  }
  for (int idx = tid; idx < 64*16; idx += 1024) {
    int r = idx >> 4, j = idx & 15;
    Hs[r*744 + 720 + j] = 0;
  }
  __syncthreads();
  // ---- fc2: wave wid<12 owns ct=wid over all 4 row-groups (pe-aligned) ----
  f4v acc2[4];
  #pragma unroll
  for (int rg = 0; rg < 4; ++rg) acc2[rg] = z;
  if (wid < 12) {
    for (int ks = 0; ks < 23; ++ks) {
      s8v bb = *(const s8v*)(wf2p + (size_t)((wid*23 + ks)*64 + lane)*8);
      #pragma unroll
      for (int rg = 0; rg < 4; ++rg) {
        s8v a0 = *(const s8v*)(Hs + (16*rg + lr)*744 + ks*32 + lg*8);
        acc2[rg] = mfma16(a0, bb, acc2[rg]);
      }
    }
  }
  float psum[4][4], psq[4][4];
  #pragma unroll
  for (int rg = 0; rg < 4; ++rg)
    #pragma unroll
    for (int i = 0; i < 4; ++i) { psum[rg][i] = 0.f; psq[rg][i] = 0.f; }
  if (wid < 12) {
    int c = wid*16 + lr;
    float bv = (c < 180) ? fcb2[c] : 0.f;
    #pragma unroll
    for (int rg = 0; rg < 4; ++rg)
      #pragma unroll
      for (int i = 0; i < 4; ++i) {
        float v = (c < 180) ? acc2[rg][i] + bv : 0.f;
        acc2[rg][i] = v;
        psum[rg][i] += v; psq[rg][i] += v*v;
      }
  }
  #pragma unroll
  for (int rg = 0; rg < 4; ++rg)
    #pragma unroll
    for (int i = 0; i < 4; ++i) {
      psum[rg][i] = rsum16(psum[rg][i]);
      psq[rg][i]  = rsum16(psq[rg][i]);
    }
  if (lr == 0 && wid < 12) {
    #pragma unroll
    for (int rg = 0; rg < 4; ++rg)
      #pragma unroll
      for (int i = 0; i < 4; ++i) {
        int row = 16*rg + lg*4 + i;
        redS[wid][row] = psum[rg][i];
        redQ[wid][row] = psq[rg][i];
      }
  }
  __syncthreads();
  #pragma unroll
  for (int rg = 0; rg < 4; ++rg)
    #pragma unroll
    for (int i = 0; i < 4; ++i) {
      int row = 16*rg + lg*4 + i;
      float s = 0.f, s2 = 0.f;
      #pragma unroll
      for (int w = 0; w < 12; ++w) { s += redS[w][row]; s2 += redQ[w][row]; }
      float m = s*(1.f/180.f);
      float var = fmaxf(s2*(1.f/180.f) - m*m, 0.f);
      float rs = rsqrtf(var + 1e-5f);
      if (wid < 12) {
        int c = wid*16 + lr;
        if (c < 180) {
          size_t o = (r0 + row)*180 + c;
          outp[o] = pval[rg][i] + (acc2[rg][i] - m)*rs*g2[c] + b2ln[c];
        }
      }
    }
}

// ---------------- launch ----------------
extern "C" void kernel_launch(void* const* d_in, const int* in_sizes, int n_in,
                              void* d_out, int out_size, void* d_ws, size_t ws_size,
                              hipStream_t stream) {
  const float* x      = (const float*)d_in[0];
  const float* qkv_w  = (const float*)d_in[1];
  const float* q_bias = (const float*)d_in[2];
  const float* v_bias = (const float*)d_in[3];
  const float* lsc    = (const float*)d_in[4];
  const float* cpb_w1 = (const float*)d_in[5];
  const float* cpb_b1 = (const float*)d_in[6];
  const float* cpb_w2 = (const float*)d_in[7];
  const float* proj_w = (const float*)d_in[8];
  const float* proj_b = (const float*)d_in[9];
  const float* n1g    = (const float*)d_in[10];
  const float* n1b    = (const float*)d_in[11];
  const float* n2g    = (const float*)d_in[12];
  const float* n2b    = (const float*)d_in[13];
  const float* fc1w   = (const float*)d_in[14];
  const float* fc1b   = (const float*)d_in[15];
  const float* fc2w   = (const float*)d_in[16];
  const float* fc2b   = (const float*)d_in[17];
  const float* p1w    = (const float*)d_in[18];
  const float* p1b    = (const float*)d_in[19];
  const float* pww    = (const float*)d_in[20];
  const float* pwb    = (const float*)d_in[21];
  const float* dww    = (const float*)d_in[22];
  const float* dwb    = (const float*)d_in[23];
  const float* ddw    = (const float*)d_in[24];
  const float* ddb    = (const float*)d_in[25];
  const float* p2w    = (const float*)d_in[26];
  const float* p2b    = (const float*)d_in[27];
  const float* vlng   = (const float*)d_in[28];
  const float* vlnb   = (const float*)d_in[29];
  const float* cbw    = (const float*)d_in[30];
  const float* cbb    = (const float*)d_in[31];
  const float* pew    = (const float*)d_in[32];
  const float* peb    = (const float*)d_in[33];
  float* out = (float*)d_out;
  char* ws = (char*)d_ws;

  float* x1   = (float*)(ws + OFF_X1);
  float* v1   = (float*)(ws + OFF_V1);
  float* ab1  = (float*)(ws + OFF_AB1);
  float* ab2  = (float*)(ws + OFF_AB2);
  unsigned short* vnb = (unsigned short*)(ws + OFF_VNB);
  unsigned short* cbn = (unsigned short*)(ws + OFF_CBN);
  float* tbl   = (float*)(ws + O_TBL);
  float* biasA = (float*)(ws + O_BIASA);
  unsigned short* wqp = (unsigned short*)(ws + O_WQ);
  unsigned short* wpjp = (unsigned short*)(ws + O_WPJ);
  unsigned short* wpep = (unsigned short*)(ws + O_WPE);
  unsigned short* wp1 = (unsigned short*)(ws + O_WP1);
  unsigned short* wpw = (unsigned short*)(ws + O_WPW);
  unsigned short* wp2 = (unsigned short*)(ws + O_WP2);
  unsigned short* wf1p = (unsigned short*)(ws + O_WF1);
  unsigned short* wf2p = (unsigned short*)(ws + O_WF2);
  unsigned short* wcbp = (unsigned short*)(ws + O_WCB);

  // prep (3 launches)
  k_cpb_tbl<<<225, 512, 0, stream>>>(cpb_w1, cpb_b1, cpb_w2, tbl);
  k_cpb_bias<<<96, 256, 0, stream>>>(tbl, biasA);
  k_prep<<<(669696 + 255)/256, 256, 0, stream>>>(qkv_w, proj_w, pew, fc1w, fc2w,
      p1w, pww, p2w, cbw, wqp, wpjp, wpep, wf1p, wf2p, wp1, wpw, wp2, wcbp);
  // main chain
  k_qa_mfma<<<NWIN, 1024, 0, stream>>>(x, wqp, q_bias, v_bias, biasA, lsc,
                                       wpjp, proj_b, n1g, n1b, x1);
  k_p1w_mfma<<<NWIN, 256, 0, stream>>>(x1, wp1, p1b, v1, wpw, pwb, ab1);
  k_dwcf<<<1536, 512, 0, stream>>>(ab1, ab2, dww, dwb, ddw, ddb);
  k_p2ln_mfma<<<NWIN, 256, 0, stream>>>(v1, ab2, x1, wp2, p2b, vlng, vlnb, vnb);
  k_cb_mfma<<<NWIN, 256, 0, stream>>>(vnb, wcbp, cbb, cbn);
  k_pef_mfma<<<NWIN, 1024, 0, stream>>>(cbn, wpep, peb, x1, out,
                                        wf1p, fc1b, wf2p, fc2b, n2g, n2b);
}

// Round 28
// 498.183 us; speedup vs baseline: 1.0856x; 1.0770x over previous
//
#include <hip/hip_runtime.h>
#include <hip/hip_bf16.h>

#define DEV __device__ __forceinline__

typedef __attribute__((ext_vector_type(8))) short s8v;   // 8 bf16 (4 VGPR)
typedef __attribute__((ext_vector_type(4))) float f4v;   // MFMA acc

static constexpr int NWIN = 1152;
static constexpr int NROW = 73728;

// ---------------- workspace layout (peak < 185.8 MB) ----
static constexpr size_t OFF_X1   = 132710400;    // f32  [NROW][180]  (live until pe/p2)
static constexpr size_t OFF_V1   = 0;            // f32  NCHW [8*96][9216]
static constexpr size_t OFF_AB1  = 28311552;     // f32  NCHW
static constexpr size_t OFF_AB2  = 84934656;     // f32  NCHW (dwcf output, no in-place race)
static constexpr size_t OFF_VNB  = 56623104;     // bf16 NHWC [NROW][192] — group-padded layout
static constexpr size_t OFF_CBN  = 0;            // bf16 NHWC [NROW][192] (over v1, dead)
static constexpr size_t WB       = 130613248;
static constexpr size_t O_TBL    = WB;                    // f32 [225][6]
static constexpr size_t O_BIASA  = WB + 8192;             // f32 [6][64][64]
static constexpr size_t O_WQ     = WB + 106496;           // bf16 packed frag-major [34*6*512]
static constexpr size_t O_WPJ    = O_WQ  + 208896;        // bf16 packed frag-major [12*6*512]
static constexpr size_t O_WPE    = O_WPJ + 73728;         // bf16 packed frag-major [12*6*512]
static constexpr size_t O_WP1    = O_WPE + 73728;         // bf16 [96][192]
static constexpr size_t O_WPW    = O_WP1 + 36864;         // bf16 [96][96]
static constexpr size_t O_WP2    = O_WPW + 18432;         // bf16 [192][96]
static constexpr size_t O_WF1    = O_WP2 + 36864;         // bf16 packed frag-major [45*6*512]
static constexpr size_t O_WF2    = O_WF1 + 282624;        // bf16 packed frag-major [12*23*512]
static constexpr size_t O_WCB    = O_WF2 + 282624;        // bf16 packed frag-major [2*9*6*3*512]

DEV float geluf(float x){ return 0.5f*x*(1.f + erff(x*0.70710678118654752f)); }

DEV unsigned short f2b(float v){
  union { __hip_bfloat16 h; unsigned short u; } x;
  x.h = __float2bfloat16(v);
  return x.u;
}

DEV float b2f(unsigned short u){
  union { float f; unsigned u; } x;
  x.u = ((unsigned)u) << 16;
  return x.f;
}

DEV f4v mfma16(s8v a, s8v b, f4v c){
  return __builtin_amdgcn_mfma_f32_16x16x32_bf16(a, b, c, 0, 0, 0);
}

DEV float rsum16(float v){
  v += __shfl_xor(v, 1); v += __shfl_xor(v, 2);
  v += __shfl_xor(v, 4); v += __shfl_xor(v, 8);
  return v;
}

DEV float rmax16(float v){
  v = fmaxf(v, __shfl_xor(v, 1)); v = fmaxf(v, __shfl_xor(v, 2));
  v = fmaxf(v, __shfl_xor(v, 4)); v = fmaxf(v, __shfl_xor(v, 8));
  return v;
}

DEV float qkvbias(int c, const float* qb, const float* vb){
  return (c < 180) ? qb[c] : (c < 360 ? 0.f : vb[c-360]);
}

DEV void pack4(unsigned short* dst, float4 v){
  unsigned p0 = (unsigned)f2b(v.x) | ((unsigned)f2b(v.y) << 16);
  unsigned p1 = (unsigned)f2b(v.z) | ((unsigned)f2b(v.w) << 16);
  uint2 pk; pk.x = p0; pk.y = p1;
  *(uint2*)dst = pk;
}

// ---------------- CPB MLP table ----------------
__global__ __launch_bounds__(512) void k_cpb_tbl(const float* __restrict__ w1,
    const float* __restrict__ b1, const float* __restrict__ w2, float* __restrict__ tbl){
  int m = blockIdx.x, tid = threadIdx.x;
  int i = m/15, j = m - (m/15)*15;
  float t0 = (float)(i-7)*(8.f/7.f), t1 = (float)(j-7)*(8.f/7.f);
  float f0 = log2f(fabsf(t0)+1.f)*(1.f/3.f); if (t0 < 0.f) f0 = -f0;
  float f1 = log2f(fabsf(t1)+1.f)*(1.f/3.f); if (t1 < 0.f) f1 = -f1;
  float hv = fmaxf(f0*w1[2*tid] + f1*w1[2*tid+1] + b1[tid], 0.f);
  __shared__ float red[6][8];
  int lane = tid & 63, wv = tid >> 6;
  for (int h = 0; h < 6; ++h) {
    float p = hv * w2[h*512 + tid];
    for (int off = 32; off; off >>= 1) p += __shfl_down(p, off);
    if (lane == 0) red[h][wv] = p;
  }
  __syncthreads();
  if (tid < 6) {
    float s = 0.f;
    for (int w = 0; w < 8; ++w) s += red[tid][w];
    tbl[m*6 + tid] = s;
  }
}

__global__ __launch_bounds__(256) void k_cpb_bias(const float* __restrict__ tbl,
    float* __restrict__ biasA){
  int idx = blockIdx.x*256 + threadIdx.x;
  if (idx >= 6*64*64) return;
  int h = idx >> 12, n = (idx >> 6) & 63, m = idx & 63;
  int dh = (n>>3) - (m>>3) + 7, dw = (n&7) - (m&7) + 7;
  float v = tbl[(dh*15 + dw)*6 + h];
  biasA[idx] = 16.f / (1.f + expf(-v));
}

// ---------------- merged weight prep (all packs + cvtpads + cb pack) ---------
DEV void pack_one(int idx, const float* __restrict__ src,
                  unsigned short* __restrict__ dst, int Ncols, int K, int KS){
  int j = idx & 7, l = (idx >> 3) & 63, f = idx >> 9;
  int ks = f - (f/KS)*KS, ct = f/KS;
  int col = ct*16 + (l & 15);
  int k = ks*32 + (l >> 4)*8 + j;
  float v = (col < Ncols && k < K) ? src[col*K + k] : 0.f;
  dst[idx] = f2b(v);
}

DEV void cvt_one(int idx, const float* __restrict__ src,
                 unsigned short* __restrict__ dst, int R, int K, int Kp){
  int r = idx / Kp, k = idx - r*Kp;
  float v = (r < R && k < K) ? src[r*K + k] : 0.f;
  dst[idx] = f2b(v);
}

DEV void packcb_one(int idx, const float* __restrict__ cbw,
                    unsigned short* __restrict__ dst){
  int j = idx & 7, l = (idx >> 3) & 63, f = idx >> 9;
  int k0 = f % 3; f /= 3;
  int cc = f % 6; f /= 6;
  int tap = f % 9; int g = f/9;
  int col = cc*16 + (l & 15);
  int k = k0*32 + (l >> 4)*8 + j;
  float v = (col < 90 && k < 90) ? cbw[((g*90 + col)*90 + k)*9 + tap] : 0.f;
  dst[idx] = f2b(v);
}

__global__ __launch_bounds__(256) void k_prep(
    const float* __restrict__ qkv_w, const float* __restrict__ proj_w,
    const float* __restrict__ pew,   const float* __restrict__ fc1w,
    const float* __restrict__ fc2w,  const float* __restrict__ p1w,
    const float* __restrict__ pww,   const float* __restrict__ p2w,
    const float* __restrict__ cbw,
    unsigned short* __restrict__ wqp,  unsigned short* __restrict__ wpjp,
    unsigned short* __restrict__ wpep, unsigned short* __restrict__ wf1p,
    unsigned short* __restrict__ wf2p, unsigned short* __restrict__ wp1,
    unsigned short* __restrict__ wpw,  unsigned short* __restrict__ wp2,
    unsigned short* __restrict__ wcbp){
  int idx = blockIdx.x*256 + threadIdx.x;
  if (idx < 104448) { pack_one(idx, qkv_w, wqp, 540, 180, 6); return; }
  idx -= 104448;
  if (idx < 36864)  { pack_one(idx, proj_w, wpjp, 180, 180, 6); return; }
  idx -= 36864;
  if (idx < 36864)  { pack_one(idx, pew, wpep, 180, 180, 6); return; }
  idx -= 36864;
  if (idx < 138240) { pack_one(idx, fc1w, wf1p, 720, 180, 6); return; }
  idx -= 138240;
  if (idx < 141312) { pack_one(idx, fc2w, wf2p, 180, 720, 23); return; }
  idx -= 141312;
  if (idx < 18432)  { cvt_one(idx, p1w, wp1, 96, 180, 192); return; }
  idx -= 18432;
  if (idx < 9216)   { cvt_one(idx, pww, wpw, 96, 96, 96); return; }
  idx -= 9216;
  if (idx < 18432)  { cvt_one(idx, p2w, wp2, 180, 96, 96); return; }
  idx -= 18432;
  if (idx < 165888) { packcb_one(idx, cbw, wcbp); return; }
}

// ---- fused qkv GEMM + window attention + proj + norm1 -> x1 (1024 thr) -----
__global__ __launch_bounds__(1024) void k_qa_mfma(const float* __restrict__ x,
    const unsigned short* __restrict__ wqp, const float* __restrict__ qb,
    const float* __restrict__ vb, const float* __restrict__ biasA,
    const float* __restrict__ lsc,
    const unsigned short* __restrict__ wpjp, const float* __restrict__ pb,
    const float* __restrict__ g1, const float* __restrict__ b1,
    float* __restrict__ x1){
  __shared__ __align__(16) unsigned short SH[73728];
  __shared__ int rowOff[64];
  float* invq = (float*)(SH + 72192);
  float* invk = (float*)(SH + 72960);
  int win = blockIdx.x, tid = threadIdx.x;
  if (tid < 64) {
    int b = win/144, rem = win - b*144, wh = rem/12, ww = rem - (rem/12)*12;
    int l = (wh*8 + (tid>>3))*96 + ww*8 + (tid&7);
    rowOff[tid] = (b*9216 + l)*180;
  }
  __syncthreads();
  for (int idx = tid; idx < 64*45; idx += 1024) {
    int i = idx/45, k4 = idx - i*45;
    float4 v = *(const float4*)(x + rowOff[i] + k4*4);
    pack4(SH + i*200 + k4*4, v);
  }
  for (int idx = tid; idx < 64*12; idx += 1024) {
    int i = idx/12, k = idx - (idx/12)*12;
    SH[i*200 + 180 + k] = 0;
  }
  __syncthreads();
  int wid = tid>>6, lane = tid&63, lr = lane&15, lg = lane>>4;
  f4v z = {0.f,0.f,0.f,0.f};
  for (int ct = wid; ct < 34; ct += 16) {
    f4v acc[4];
    #pragma unroll
    for (int rg = 0; rg < 4; ++rg) acc[rg] = z;
    #pragma unroll
    for (int k0 = 0; k0 < 6; ++k0) {
      s8v b = *(const s8v*)(wqp + (size_t)((ct*6 + k0)*64 + lane)*8);
      #pragma unroll
      for (int rg = 0; rg < 4; ++rg) {
        s8v a = *(const s8v*)(SH + (16*rg + lr)*200 + k0*32 + lg*8);
        acc[rg] = mfma16(a, b, acc[rg]);
      }
    }
    int c = ct*16 + lr;
    if (c < 540) {
      float bias = qkvbias(c, qb, vb);
      int base, d, isV = 0;
      if (c < 180)      { int h = c/30;        d = c - h*30;        base = 27648 + h*2560; }
      else if (c < 360) { int h = (c-180)/30;  d = (c-180) - h*30;  base = 43008 + h*2560; }
      else              { int h = (c-360)/30;  d = (c-360) - h*30;  base = 58368 + h*2304; isV = 1; }
      #pragma unroll
      for (int rg = 0; rg < 4; ++rg)
        #pragma unroll
        for (int i = 0; i < 4; ++i) {
          int n = 16*rg + lg*4 + i;
          int addr = isV ? (base + d*72 + n) : (base + n*40 + d);
          SH[addr] = f2b(acc[rg][i] + bias);
        }
    }
  }
  __syncthreads();
  for (int j = tid; j < 1536; j += 1024) {
    int tensor = j >= 768;
    int rem = j - tensor*768;
    int h = rem >> 7, r2 = rem & 127;
    int n = r2 >> 1, d = 30 + (r2 & 1);
    SH[(tensor ? 43008 : 27648) + h*2560 + n*40 + d] = 0;
  }
  for (int j = tid; j < 864; j += 1024) {
    int h = j/144, rem = j - h*144;
    int d = 30 + rem/72, m = rem - (rem/72)*72;
    SH[58368 + h*2304 + d*72 + m] = 0;
  }
  for (int j = tid; j < 768; j += 1024) {
    int tensor = j >= 384;
    int rem = j - tensor*384;
    const unsigned short* basep = SH + (tensor ? 43008 : 27648)
                                     + (rem >> 6)*2560 + (rem & 63)*40;
    float s = 0.f;
    for (int d = 0; d < 30; ++d) { float v = b2f(basep[d]); s += v*v; }
    float inv = 1.f / fmaxf(sqrtf(s), 1e-12f);
    (tensor ? invk : invq)[rem] = inv;
  }
  __syncthreads();
  f4v oa0[2], oa1[2];
  #pragma unroll
  for (int tt = 0; tt < 2; ++tt) {
    int t = wid + tt*16;
    if (t < 24) {
      int h = t >> 2, rb = t & 3;
      float scale = __expf(fminf(lsc[h], 4.6051701859880914f));
      const unsigned short* Qh = SH + 27648 + h*2560;
      const unsigned short* Kh = SH + 43008 + h*2560;
      const unsigned short* Vh = SH + 58368 + h*2304;
      unsigned short* Ph = SH + h*4608;
      s8v aq = *(const s8v*)(Qh + (16*rb + lr)*40 + lg*8);
      f4v sacc[4];
      #pragma unroll
      for (int tc = 0; tc < 4; ++tc) {
        s8v bk = *(const s8v*)(Kh + (16*tc + lr)*40 + lg*8);
        sacc[tc] = mfma16(aq, bk, z);
      }
      float iq[4], ikv[4];
      #pragma unroll
      for (int i = 0; i < 4; ++i) iq[i] = invq[h*64 + 16*rb + lg*4 + i] * scale;
      #pragma unroll
      for (int tc = 0; tc < 4; ++tc) ikv[tc] = invk[h*64 + 16*tc + lr];
      float p[4][4];
      #pragma unroll
      for (int tc = 0; tc < 4; ++tc) {
        int col = 16*tc + lr;
        #pragma unroll
        for (int i = 0; i < 4; ++i) {
          int row = 16*rb + lg*4 + i;
          p[tc][i] = sacc[tc][i]*iq[i]*ikv[tc] + biasA[((h*64 + row) << 6) + col];
        }
      }
      float rin[4];
      #pragma unroll
      for (int i = 0; i < 4; ++i) {
        float mx = fmaxf(fmaxf(p[0][i], p[1][i]), fmaxf(p[2][i], p[3][i]));
        mx = rmax16(mx);
        float sum = 0.f;
        #pragma unroll
        for (int tc = 0; tc < 4; ++tc) { p[tc][i] = __expf(p[tc][i] - mx); sum += p[tc][i]; }
        sum = rsum16(sum);
        rin[i] = 1.f / sum;
      }
      #pragma unroll
      for (int tc = 0; tc < 4; ++tc)
        #pragma unroll
        for (int i = 0; i < 4; ++i)
          Ph[(16*rb + lg*4 + i)*72 + 16*tc + lr] = f2b(p[tc][i]*rin[i]);
      f4v o0 = z, o1 = z;
      #pragma unroll
      for (int k0 = 0; k0 < 2; ++k0) {
        s8v pa = *(const s8v*)(Ph + (16*rb + lr)*72 + k0*32 + lg*8);
        s8v b0 = *(const s8v*)(Vh + lr*72        + k0*32 + lg*8);
        s8v b1 = *(const s8v*)(Vh + (16 + lr)*72 + k0*32 + lg*8);
        o0 = mfma16(pa, b0, o0);
        o1 = mfma16(pa, b1, o1);
      }
      oa0[tt] = o0; oa1[tt] = o1;
    }
  }
  __syncthreads();
  unsigned short* Aw = SH + 43008;
  #pragma unroll
  for (int tt = 0; tt < 2; ++tt) {
    int t = wid + tt*16;
    if (t < 24) {
      int h = t >> 2, rb = t & 3;
      #pragma unroll
      for (int i = 0; i < 4; ++i) {
        int row = 16*rb + lg*4 + i;
        Aw[row*200 + h*30 + lr] = f2b(oa0[tt][i]);
        int c1 = 16 + lr;
        if (c1 < 30) Aw[row*200 + h*30 + c1] = f2b(oa1[tt][i]);
      }
    }
  }
  for (int idx = tid; idx < 64*12; idx += 1024) {
    int r = idx/12, j = idx - (idx/12)*12;
    Aw[r*200 + 180 + j] = 0;
  }
  __syncthreads();
  float* redS = (float*)(SH + 58368);
  float* redQ = (float*)(SH + 58368 + 1536*4);
  f4v pacc[4];
  #pragma unroll
  for (int rg = 0; rg < 4; ++rg) pacc[rg] = z;
  if (wid < 12) {
    #pragma unroll
    for (int k0 = 0; k0 < 6; ++k0) {
      s8v b = *(const s8v*)(wpjp + (size_t)((wid*6 + k0)*64 + lane)*8);
      #pragma unroll
      for (int rg = 0; rg < 4; ++rg) {
        s8v a = *(const s8v*)(Aw + (16*rg + lr)*200 + k0*32 + lg*8);
        pacc[rg] = mfma16(a, b, pacc[rg]);
      }
    }
  }
  float psum[4][4], psq[4][4];
  #pragma unroll
  for (int rg = 0; rg < 4; ++rg)
    #pragma unroll
    for (int i = 0; i < 4; ++i) { psum[rg][i] = 0.f; psq[rg][i] = 0.f; }
  if (wid < 12) {
    int c = wid*16 + lr;
    float bv = (c < 180) ? pb[c] : 0.f;
    #pragma unroll
    for (int rg = 0; rg < 4; ++rg)
      #pragma unroll
      for (int i = 0; i < 4; ++i) {
        float v = (c < 180) ? pacc[rg][i] + bv : 0.f;
        pacc[rg][i] = v;
        psum[rg][i] += v; psq[rg][i] += v*v;
      }
  }
  #pragma unroll
  for (int rg = 0; rg < 4; ++rg)
    #pragma unroll
    for (int i = 0; i < 4; ++i) {
      psum[rg][i] = rsum16(psum[rg][i]);
      psq[rg][i]  = rsum16(psq[rg][i]);
    }
  if (lr == 0 && wid < 12) {
    #pragma unroll
    for (int rg = 0; rg < 4; ++rg)
      #pragma unroll
      for (int i = 0; i < 4; ++i) {
        int row = 16*rg + lg*4 + i;
        redS[wid*64 + row] = psum[rg][i];
        redQ[wid*64 + row] = psq[rg][i];
      }
  }
  __syncthreads();
  #pragma unroll
  for (int rg = 0; rg < 4; ++rg)
    #pragma unroll
    for (int i = 0; i < 4; ++i) {
      int row = 16*rg + lg*4 + i;
      float s = 0.f, s2 = 0.f;
      #pragma unroll
      for (int w = 0; w < 12; ++w) { s += redS[w*64 + row]; s2 += redQ[w*64 + row]; }
      float m = s*(1.f/180.f);
      float var = fmaxf(s2*(1.f/180.f) - m*m, 0.f);
      float rs = rsqrtf(var + 1e-5f);
      if (wid < 12) {
        int c = wid*16 + lr;
        if (c < 180) {
          size_t o = (size_t)rowOff[row] + c;
          x1[o] = x[o] + (pacc[rg][i] - m)*rs*g1[c] + b1[c];
        }
      }
    }
}

// ---------------- fused VAB p1 + pw: x1 -> v1 (f32, global) and ab1 ----------
__global__ __launch_bounds__(256) void k_p1w_mfma(const float* __restrict__ x1,
    const unsigned short* __restrict__ wp1, const float* __restrict__ b1p,
    float* __restrict__ v1,
    const unsigned short* __restrict__ wpw, const float* __restrict__ bpw,
    float* __restrict__ ab1){
  __shared__ __align__(16) unsigned short A[64*200];
  __shared__ __align__(16) unsigned short A2[64*104];
  int blk = blockIdx.x, tid = threadIdx.x;
  int b = blk/144, p0 = (blk - b*144)*64;
  int rowb = b*9216 + p0;
  for (int idx = tid; idx < 64*45; idx += 256) {
    int i = idx/45, k4 = idx - i*45;
    float4 v = *(const float4*)(x1 + (size_t)(rowb + i)*180 + k4*4);
    pack4(A + i*200 + k4*4, v);
  }
  for (int idx = tid; idx < 64*12; idx += 256) {
    int i = idx/12, k = idx - (idx/12)*12;
    A[i*200 + 180 + k] = 0;
  }
  __syncthreads();
  int wid = tid>>6, lane = tid&63, lr = lane&15, lg = lane>>4;
  const unsigned short* arow = A + (16*wid + lr)*200 + lg*8;
  f4v z = {0.f,0.f,0.f,0.f};
  #pragma unroll
  for (int pp = 0; pp < 3; ++pp) {
    int c0 = pp*32;
    f4v acc0 = z, acc1 = z;
    #pragma unroll
    for (int k0 = 0; k0 < 6; ++k0) {
      s8v a  = *(const s8v*)(arow + k0*32);
      s8v b0 = *(const s8v*)(wp1 + (size_t)(c0 + lr)*192 + k0*32 + lg*8);
      s8v b1 = *(const s8v*)(wp1 + (size_t)(c0 + 16 + lr)*192 + k0*32 + lg*8);
      acc0 = mfma16(a, b0, acc0);
      acc1 = mfma16(a, b1, acc1);
    }
    int c  = c0 + lr, c2 = c0 + 16 + lr;
    float bv = b1p[c], bv2 = b1p[c2];
    #pragma unroll
    for (int i = 0; i < 4; ++i) {
      int px = 16*wid + lg*4 + i;
      float g0 = geluf(acc0[i] + bv );
      float g1 = geluf(acc1[i] + bv2);
      v1[(size_t)(b*96 + c )*9216 + p0 + px] = g0;
      v1[(size_t)(b*96 + c2)*9216 + p0 + px] = g1;
      A2[px*104 + c ] = f2b(g0);
      A2[px*104 + c2] = f2b(g1);
    }
  }
  __syncthreads();
  const unsigned short* arow2 = A2 + (16*wid + lr)*104 + lg*8;
  #pragma unroll
  for (int pp = 0; pp < 3; ++pp) {
    int c0 = pp*32;
    f4v acc0 = z, acc1 = z;
    #pragma unroll
    for (int k0 = 0; k0 < 3; ++k0) {
      s8v a  = *(const s8v*)(arow2 + k0*32);
      s8v b0 = *(const s8v*)(wpw + (size_t)(c0 + lr)*96 + k0*32 + lg*8);
      s8v b1 = *(const s8v*)(wpw + (size_t)(c0 + 16 + lr)*96 + k0*32 + lg*8);
      acc0 = mfma16(a, b0, acc0);
      acc1 = mfma16(a, b1, acc1);
    }
    int c  = c0 + lr, c2 = c0 + 16 + lr;
    float bv = bpw[c], bv2 = bpw[c2];
    #pragma unroll
    for (int i = 0; i < 4; ++i) {
      int px = 16*wid + lg*4 + i;
      ab1[(size_t)(b*96 + c )*9216 + p0 + px] = acc0[i] + bv;
      ab1[(size_t)(b*96 + c2)*9216 + p0 + px] = acc1[i] + bv2;
    }
  }
}

// ---------------- depthwise 5x5 pair, half-plane split w/ halo: ab1 -> ab2 ---
__global__ __launch_bounds__(512) void k_dwcf(const float* __restrict__ ab1,
    float* __restrict__ ab2,
    const float* __restrict__ w1, const float* __restrict__ b1,
    const float* __restrict__ w2, const float* __restrict__ b2){
  __shared__ float P0[56*96];
  __shared__ float P1[54*96];
  int blk = blockIdx.x;
  int bc = blk >> 1, half = blk & 1;     // bc = b*96 + c
  int c = bc - (bc/96)*96;
  int tid = threadIdx.x;
  int h0 = half*48;
  int r0p = half ? 40 : 0;               // P0 rows [r0p, r0p+56)
  int r0q = half ? 42 : 0;               // P1 rows [r0q, r0q+54)
  const float* gp = ab1 + (size_t)bc*9216;
  float* go = ab2 + (size_t)bc*9216;
  const float4* src4 = (const float4*)(gp + r0p*96);
  for (int i = tid; i < 56*24; i += 512)
    ((float4*)P0)[i] = src4[i];
  __syncthreads();
  const float* wc1 = w1 + c*25;
  float bv1 = b1[c];
  for (int idx = tid; idx < 54*96; idx += 512) {
    int y = r0q + idx/96, xx0 = idx - (idx/96)*96;
    float acc = bv1;
    #pragma unroll
    for (int i = 0; i < 5; ++i) {
      int yy = y + (i-2);
      if (yy < 0 || yy >= 96) continue;
      const float* row = P0 + (yy - r0p)*96;
      #pragma unroll
      for (int j = 0; j < 5; ++j) {
        int xq = xx0 + (j-2);
        if (xq >= 0 && xq < 96) acc += row[xq]*wc1[i*5 + j];
      }
    }
    P1[(y - r0q)*96 + xx0] = acc;
  }
  __syncthreads();
  const float* wc2 = w2 + c*25;
  float bv2 = b2[c];
  for (int idx = tid; idx < 48*96; idx += 512) {
    int y = h0 + idx/96, xx0 = idx - (idx/96)*96;
    float acc = bv2;
    #pragma unroll
    for (int i = 0; i < 5; ++i) {
      int yy = y + 3*(i-2);
      if (yy < 0 || yy >= 96) continue;
      const float* row = P1 + (yy - r0q)*96;
      #pragma unroll
      for (int j = 0; j < 5; ++j) {
        int xq = xx0 + 3*(j-2);
        if (xq >= 0 && xq < 96) acc += row[xq]*wc2[i*5 + j];
      }
    }
    go[y*96 + xx0] = acc;
  }
}

// ---------------- p2 + residual + VAB-LN -> vnb NHWC bf16 (group-padded) -----
__global__ __launch_bounds__(256) void k_p2ln_mfma(const float* __restrict__ v1,
    const float* __restrict__ a3, const float* __restrict__ x1,
    const unsigned short* __restrict__ wp2, const float* __restrict__ bias,
    const float* __restrict__ lng, const float* __restrict__ lnb,
    unsigned short* __restrict__ vnb){
  __shared__ unsigned short A[64*104];
  int blk = blockIdx.x, tid = threadIdx.x;
  int b = blk/144, p0 = (blk - b*144)*64;
  for (int idx = tid; idx < 96*16; idx += 256) {
    int k = idx >> 4, i4 = (idx & 15)*4;
    size_t o = (size_t)(b*96 + k)*9216 + p0 + i4;
    float4 va = *(const float4*)(v1 + o);
    float4 vb = *(const float4*)(a3 + o);
    A[(i4+0)*104 + k] = f2b(va.x*vb.x);
    A[(i4+1)*104 + k] = f2b(va.y*vb.y);
    A[(i4+2)*104 + k] = f2b(va.z*vb.z);
    A[(i4+3)*104 + k] = f2b(va.w*vb.w);
  }
  __syncthreads();
  int wid = tid>>6, lane = tid&63, lr = lane&15, lg = lane>>4;
  const unsigned short* arow = A + (16*wid + lr)*104 + lg*8;
  f4v z = {0.f,0.f,0.f,0.f};
  f4v acc[12];
  #pragma unroll
  for (int cc = 0; cc < 12; ++cc) acc[cc] = z;
  #pragma unroll
  for (int k0 = 0; k0 < 3; ++k0) {
    s8v a = *(const s8v*)(arow + k0*32);
    #pragma unroll
    for (int cc = 0; cc < 12; ++cc) {
      s8v bb = *(const s8v*)(wp2 + (size_t)(cc*16 + lr)*96 + k0*32 + lg*8);
      acc[cc] = mfma16(a, bb, acc[cc]);
    }
  }
  float psum[4] = {0,0,0,0}, psq[4] = {0,0,0,0};
  #pragma unroll
  for (int cc = 0; cc < 12; ++cc) {
    int c = cc*16 + lr;
    float bv = (c < 180) ? bias[c] : 0.f;
    #pragma unroll
    for (int i = 0; i < 4; ++i) {
      int px = 16*wid + lg*4 + i;
      float v = 0.f;
      if (c < 180) v = acc[cc][i] + bv + x1[(size_t)(b*9216 + p0 + px)*180 + c];
      acc[cc][i] = v;
      psum[i] += v; psq[i] += v*v;
    }
  }
  float m[4], rs[4];
  #pragma unroll
  for (int i = 0; i < 4; ++i) {
    float s = rsum16(psum[i]), s2 = rsum16(psq[i]);
    m[i] = s*(1.f/180.f);
    float var = fmaxf(s2*(1.f/180.f) - m[i]*m[i], 0.f);
    rs[i] = rsqrtf(var + 1e-5f);
  }
  #pragma unroll
  for (int cc = 0; cc < 12; ++cc) {
    int c = cc*16 + lr;
    if (c < 180) {
      int cpos = c + (c >= 90 ? 6 : 0);
      #pragma unroll
      for (int i = 0; i < 4; ++i) {
        int px = 16*wid + lg*4 + i;
        vnb[(size_t)(b*9216 + p0 + px)*192 + cpos] =
            f2b((acc[cc][i] - m[i])*rs[i]*lng[c] + lnb[c]);
      }
    }
  }
  for (int idx = tid; idx < 64*12; idx += 256) {
    int px = idx/12, j = idx - (idx/12)*12;
    int pos = (j < 6) ? (90 + j) : (180 + j);
    vnb[(size_t)(b*9216 + p0 + px)*192 + pos] = 0;
  }
}

// ---------------- convbody: 8x8 tile, halo once, wave-owns-(g,cc3), packed B -
__global__ __launch_bounds__(256) void k_cb_mfma(const unsigned short* __restrict__ vnb,
    const unsigned short* __restrict__ wcbp, const float* __restrict__ bias,
    unsigned short* __restrict__ cbn){
  __shared__ __align__(16) unsigned short S[100*200];   // 10x10 halo x 192ch, stride 200
  int blk = blockIdx.x, tid = threadIdx.x;
  int b = blk/144, t = blk - b*144;
  int th = t/12, tw = t - (t/12)*12;
  int h0 = th*8, w0 = tw*8;
  for (int idx = tid; idx < 2400; idx += 256) {
    int pix = idx/24, chunk = idx - pix*24;
    int hp = pix/10, wp = pix - hp*10;
    int h = h0 + hp - 1, w = w0 + wp - 1;
    s8v v = {0,0,0,0,0,0,0,0};
    if (h >= 0 && h < 96 && w >= 0 && w < 96)
      v = *(const s8v*)(vnb + (size_t)(b*9216 + h*96 + w)*192 + chunk*8);
    *(s8v*)(S + pix*200 + chunk*8) = v;
  }
  __syncthreads();
  int wid = tid>>6, lane = tid&63, lr = lane&15, lg = lane>>4;
  int g = wid >> 1, ccb = (wid & 1)*3;
  f4v z = {0.f,0.f,0.f,0.f};
  f4v acc[3][4];
  #pragma unroll
  for (int t3 = 0; t3 < 3; ++t3)
    #pragma unroll
    for (int rg = 0; rg < 4; ++rg) acc[t3][rg] = z;
  #pragma unroll
  for (int tap = 0; tap < 9; ++tap) {
    int dh = tap/3 - 1, dw = tap - (tap/3)*3 - 1;
    #pragma unroll
    for (int k0 = 0; k0 < 3; ++k0) {
      s8v a0, a1, a2, a3;
      {
        int base_k = g*96 + k0*32 + lg*8;
        int ai0 = lr;
        a0 = *(const s8v*)(S + (((ai0>>3)+1+dh)*10 + (ai0&7)+1+dw)*200 + base_k);
        int ai1 = 16 + lr;
        a1 = *(const s8v*)(S + (((ai1>>3)+1+dh)*10 + (ai1&7)+1+dw)*200 + base_k);
        int ai2 = 32 + lr;
        a2 = *(const s8v*)(S + (((ai2>>3)+1+dh)*10 + (ai2&7)+1+dw)*200 + base_k);
        int ai3 = 48 + lr;
        a3 = *(const s8v*)(S + (((ai3>>3)+1+dh)*10 + (ai3&7)+1+dw)*200 + base_k);
      }
      #pragma unroll
      for (int t3 = 0; t3 < 3; ++t3) {
        int cc = ccb + t3;
        s8v bb = *(const s8v*)(wcbp + (size_t)((((g*9 + tap)*6 + cc)*3 + k0)*64 + lane)*8);
        acc[t3][0] = mfma16(a0, bb, acc[t3][0]);
        acc[t3][1] = mfma16(a1, bb, acc[t3][1]);
        acc[t3][2] = mfma16(a2, bb, acc[t3][2]);
        acc[t3][3] = mfma16(a3, bb, acc[t3][3]);
      }
    }
  }
  #pragma unroll
  for (int t3 = 0; t3 < 3; ++t3) {
    int c = (ccb + t3)*16 + lr;
    if (c < 90) {
      int o = g*90 + c;
      float bv = bias[o];
      #pragma unroll
      for (int rg = 0; rg < 4; ++rg)
        #pragma unroll
        for (int i = 0; i < 4; ++i) {
          int oi = 16*rg + lg*4 + i;
          int oy = oi>>3, ox = oi&7;
          cbn[(size_t)(b*9216 + (h0+oy)*96 + (w0+ox))*192 + o] = f2b(acc[t3][rg][i] + bv);
        }
    }
  }
  for (int idx = tid; idx < 64*12; idx += 256) {
    int pxi = idx/12, j = idx - (idx/12)*12;
    int oy = pxi>>3, ox = pxi&7;
    cbn[(size_t)(b*9216 + (h0+oy)*96 + (w0+ox))*192 + 180 + j] = 0;
  }
}

// ---------------- fused pe + MLP (1024 thr, 16 waves): cbn -> out ------------
__global__ __launch_bounds__(1024) void k_pef_mfma(const unsigned short* __restrict__ cbn,
    const unsigned short* __restrict__ wpep, const float* __restrict__ peb,
    const float* __restrict__ x1, float* __restrict__ outp,
    const unsigned short* __restrict__ wf1p, const float* __restrict__ b1f,
    const unsigned short* __restrict__ wf2p, const float* __restrict__ fcb2,
    const float* __restrict__ g2, const float* __restrict__ b2ln){
  __shared__ __align__(16) unsigned short A[64*200];
  __shared__ __align__(16) unsigned short Hs[64*744];
  __shared__ float redS[4][64], redQ[4][64];
  int blk = blockIdx.x, tid = threadIdx.x;
  int b = blk/144, p0 = (blk - b*144)*64;
  size_t r0 = (size_t)(b*9216 + p0);
  for (int idx = tid; idx < 64*24; idx += 1024) {
    int i = idx/24, ch = idx - i*24;
    *(s8v*)(A + i*200 + ch*8) = *(const s8v*)(cbn + (r0 + i)*192 + ch*8);
  }
  __syncthreads();
  int wid = tid>>6, lane = tid&63, lr = lane&15, lg = lane>>4;
  f4v z = {0.f,0.f,0.f,0.f};
  // ---- pe GEMM: one ct per wave (waves 0..11 active) ----
  f4v peacc[4];
  #pragma unroll
  for (int rg = 0; rg < 4; ++rg) peacc[rg] = z;
  if (wid < 12) {
    #pragma unroll
    for (int k0 = 0; k0 < 6; ++k0) {
      s8v bb = *(const s8v*)(wpep + (size_t)((wid*6 + k0)*64 + lane)*8);
      #pragma unroll
      for (int rg = 0; rg < 4; ++rg) {
        s8v a = *(const s8v*)(A + (16*rg + lr)*200 + k0*32 + lg*8);
        peacc[rg] = mfma16(a, bb, peacc[rg]);
      }
    }
  }
  __syncthreads();   // A reads done; A becomes pe-out staging (bf16 val)
  if (wid < 12) {
    int c = wid*16 + lr;
    if (c < 180) {
      float bv = peb[c];
      #pragma unroll
      for (int rg = 0; rg < 4; ++rg)
        #pragma unroll
        for (int i = 0; i < 4; ++i) {
          int row = 16*rg + lg*4 + i;
          size_t o = (r0 + row)*180 + c;
          float val = x1[o] + peacc[rg][i] + bv;
          outp[o] = val;
          A[row*200 + c] = f2b(val);
        }
    }
  }
  for (int idx = tid; idx < 64*20; idx += 1024) {
    int r = idx/20, j = idx - (idx/20)*20;
    A[r*200 + 180 + j] = 0;
  }
  __syncthreads();
  // ---- fc1: 45 ct over 16 waves (3 rounds) ----
  for (int ct = wid; ct < 45; ct += 16) {
    f4v acc[4];
    #pragma unroll
    for (int rg = 0; rg < 4; ++rg) acc[rg] = z;
    #pragma unroll
    for (int k0 = 0; k0 < 6; ++k0) {
      s8v bb = *(const s8v*)(wf1p + (size_t)((ct*6 + k0)*64 + lane)*8);
      #pragma unroll
      for (int rg = 0; rg < 4; ++rg) {
        s8v a = *(const s8v*)(A + (16*rg + lr)*200 + k0*32 + lg*8);
        acc[rg] = mfma16(a, bb, acc[rg]);
      }
    }
    int c = ct*16 + lr;
    float bv = b1f[c];
    #pragma unroll
    for (int rg = 0; rg < 4; ++rg)
      #pragma unroll
      for (int i = 0; i < 4; ++i)
        Hs[(16*rg + lg*4 + i)*744 + c] = f2b(geluf(acc[rg][i] + bv));
  }
  for (int idx = tid; idx < 64*16; idx += 1024) {
    int r = idx >> 4, j = idx & 15;
    Hs[r*744 + 720 + j] = 0;
  }
  __syncthreads();
  // ---- fc2: wave (cw, rb) owns 3 ct x 1 row-block of 16 ----
  int cw = wid & 3, rb = wid >> 2;
  f4v acc2[3];
  #pragma unroll
  for (int t3 = 0; t3 < 3; ++t3) acc2[t3] = z;
  for (int ks = 0; ks < 23; ++ks) {
    s8v a0 = *(const s8v*)(Hs + (rb*16 + lr)*744 + ks*32 + lg*8);
    #pragma unroll
    for (int t3 = 0; t3 < 3; ++t3) {
      int ct = cw + t3*4;
      s8v bb = *(const s8v*)(wf2p + (size_t)((ct*23 + ks)*64 + lane)*8);
      acc2[t3] = mfma16(a0, bb, acc2[t3]);
    }
  }
  float psum[4] = {0,0,0,0}, psq[4] = {0,0,0,0};
  #pragma unroll
  for (int t3 = 0; t3 < 3; ++t3) {
    int c = (cw + t3*4)*16 + lr;
    float bv = (c < 180) ? fcb2[c] : 0.f;
    #pragma unroll
    for (int i = 0; i < 4; ++i) {
      float v = (c < 180) ? acc2[t3][i] + bv : 0.f;
      acc2[t3][i] = v;
      psum[i] += v; psq[i] += v*v;
    }
  }
  #pragma unroll
  for (int i = 0; i < 4; ++i) {
    psum[i] = rsum16(psum[i]);
    psq[i]  = rsum16(psq[i]);
  }
  if (lr == 0) {
    #pragma unroll
    for (int i = 0; i < 4; ++i) {
      int row = rb*16 + lg*4 + i;
      redS[cw][row] = psum[i];
      redQ[cw][row] = psq[i];
    }
  }
  __syncthreads();
  #pragma unroll
  for (int i = 0; i < 4; ++i) {
    int row = rb*16 + lg*4 + i;
    float s  = redS[0][row] + redS[1][row] + redS[2][row] + redS[3][row];
    float s2 = redQ[0][row] + redQ[1][row] + redQ[2][row] + redQ[3][row];
    float m = s*(1.f/180.f);
    float var = fmaxf(s2*(1.f/180.f) - m*m, 0.f);
    float rs = rsqrtf(var + 1e-5f);
    #pragma unroll
    for (int t3 = 0; t3 < 3; ++t3) {
      int c = (cw + t3*4)*16 + lr;
      if (c < 180) {
        size_t o = (r0 + row)*180 + c;
        outp[o] = outp[o] + (acc2[t3][i] - m)*rs*g2[c] + b2ln[c];
      }
    }
  }
}

// ---------------- launch ----------------
extern "C" void kernel_launch(void* const* d_in, const int* in_sizes, int n_in,
                              void* d_out, int out_size, void* d_ws, size_t ws_size,
                              hipStream_t stream) {
  const float* x      = (const float*)d_in[0];
  const float* qkv_w  = (const float*)d_in[1];
  const float* q_bias = (const float*)d_in[2];
  const float* v_bias = (const float*)d_in[3];
  const float* lsc    = (const float*)d_in[4];
  const float* cpb_w1 = (const float*)d_in[5];
  const float* cpb_b1 = (const float*)d_in[6];
  const float* cpb_w2 = (const float*)d_in[7];
  const float* proj_w = (const float*)d_in[8];
  const float* proj_b = (const float*)d_in[9];
  const float* n1g    = (const float*)d_in[10];
  const float* n1b    = (const float*)d_in[11];
  const float* n2g    = (const float*)d_in[12];
  const float* n2b    = (const float*)d_in[13];
  const float* fc1w   = (const float*)d_in[14];
  const float* fc1b   = (const float*)d_in[15];
  const float* fc2w   = (const float*)d_in[16];
  const float* fc2b   = (const float*)d_in[17];
  const float* p1w    = (const float*)d_in[18];
  const float* p1b    = (const float*)d_in[19];
  const float* pww    = (const float*)d_in[20];
  const float* pwb    = (const float*)d_in[21];
  const float* dww    = (const float*)d_in[22];
  const float* dwb    = (const float*)d_in[23];
  const float* ddw    = (const float*)d_in[24];
  const float* ddb    = (const float*)d_in[25];
  const float* p2w    = (const float*)d_in[26];
  const float* p2b    = (const float*)d_in[27];
  const float* vlng   = (const float*)d_in[28];
  const float* vlnb   = (const float*)d_in[29];
  const float* cbw    = (const float*)d_in[30];
  const float* cbb    = (const float*)d_in[31];
  const float* pew    = (const float*)d_in[32];
  const float* peb    = (const float*)d_in[33];
  float* out = (float*)d_out;
  char* ws = (char*)d_ws;

  float* x1   = (float*)(ws + OFF_X1);
  float* v1   = (float*)(ws + OFF_V1);
  float* ab1  = (float*)(ws + OFF_AB1);
  float* ab2  = (float*)(ws + OFF_AB2);
  unsigned short* vnb = (unsigned short*)(ws + OFF_VNB);
  unsigned short* cbn = (unsigned short*)(ws + OFF_CBN);
  float* tbl   = (float*)(ws + O_TBL);
  float* biasA = (float*)(ws + O_BIASA);
  unsigned short* wqp = (unsigned short*)(ws + O_WQ);
  unsigned short* wpjp = (unsigned short*)(ws + O_WPJ);
  unsigned short* wpep = (unsigned short*)(ws + O_WPE);
  unsigned short* wp1 = (unsigned short*)(ws + O_WP1);
  unsigned short* wpw = (unsigned short*)(ws + O_WPW);
  unsigned short* wp2 = (unsigned short*)(ws + O_WP2);
  unsigned short* wf1p = (unsigned short*)(ws + O_WF1);
  unsigned short* wf2p = (unsigned short*)(ws + O_WF2);
  unsigned short* wcbp = (unsigned short*)(ws + O_WCB);

  // prep (3 launches)
  k_cpb_tbl<<<225, 512, 0, stream>>>(cpb_w1, cpb_b1, cpb_w2, tbl);
  k_cpb_bias<<<96, 256, 0, stream>>>(tbl, biasA);
  k_prep<<<(669696 + 255)/256, 256, 0, stream>>>(qkv_w, proj_w, pew, fc1w, fc2w,
      p1w, pww, p2w, cbw, wqp, wpjp, wpep, wf1p, wf2p, wp1, wpw, wp2, wcbp);
  // main chain
  k_qa_mfma<<<NWIN, 1024, 0, stream>>>(x, wqp, q_bias, v_bias, biasA, lsc,
                                       wpjp, proj_b, n1g, n1b, x1);
  k_p1w_mfma<<<NWIN, 256, 0, stream>>>(x1, wp1, p1b, v1, wpw, pwb, ab1);
  k_dwcf<<<1536, 512, 0, stream>>>(ab1, ab2, dww, dwb, ddw, ddb);
  k_p2ln_mfma<<<NWIN, 256, 0, stream>>>(v1, ab2, x1, wp2, p2b, vlng, vlnb, vnb);
  k_cb_mfma<<<NWIN, 256, 0, stream>>>(vnb, wcbp, cbb, cbn);
  k_pef_mfma<<<NWIN, 1024, 0, stream>>>(cbn, wpep, peb, x1, out,
                                        wf1p, fc1b, wf2p, fc2b, n2g, n2b);
}